// Round 2
// baseline (1592.381 us; speedup 1.0000x reference)
//
#include <hip/hip_runtime.h>
#include <hip/hip_bf16.h>

#define NPIX 4096   // H*W
#define NCH  256    // input channels
#define CI   128    // inter channels
#define EPS  1e-5f

typedef unsigned short u16;

// ---------- bf16 bit helpers (ws intermediates stored as bf16 bits) ----------
__device__ __forceinline__ float bfu2f(u16 u) {
    union { unsigned int i; float f; } x; x.i = ((unsigned int)u) << 16; return x.f;
}
__device__ __forceinline__ u16 f2bfu(float f) {
    union { float ff; unsigned int i; } x; x.ff = f;
    unsigned int r = x.i + 0x7FFFu + ((x.i >> 16) & 1u);
    return (u16)(r >> 16);
}

// =====================================================================
// Kernel 1: all 1x1 convolutions (+BN for the t-branches). fp32 in,
// bf16-bits out to ws, layout [b][ch][n].
// Block: 8 output channels x 256 pixels, dot over C=256. Weights in LDS.
// =====================================================================
__global__ __launch_bounds__(256) void proj_kernel(
    const float* __restrict__ xq, const float* __restrict__ xs,
    const float* __restrict__ w_v,  const float* __restrict__ b_v,
    const float* __restrict__ w_k1, const float* __restrict__ b_k1,
    const float* __restrict__ w_q1, const float* __restrict__ b_q1,
    const float* __restrict__ w_k2, const float* __restrict__ b_k2,
    const float* __restrict__ w_q2, const float* __restrict__ b_q2,
    const float* __restrict__ w_ts, const float* __restrict__ b_ts,
    const float* __restrict__ g_ts, const float* __restrict__ be_ts,
    const float* __restrict__ m_ts, const float* __restrict__ v_ts,
    const float* __restrict__ w_tq, const float* __restrict__ b_tq,
    const float* __restrict__ g_tq, const float* __restrict__ be_tq,
    const float* __restrict__ m_tq, const float* __restrict__ v_tq,
    u16* __restrict__ kT, u16* __restrict__ qT,
    u16* __restrict__ vq, u16* __restrict__ vs,
    u16* __restrict__ tq, u16* __restrict__ ts)
{
    __shared__ float wsh[8][256];

    const int tid = threadIdx.x;
    const int n   = blockIdx.x * 256 + tid;            // pixel
    const int og  = blockIdx.y;                        // 0..47  (o = og*8)
    const int bz  = blockIdx.z;                        // 0..3
    const int b   = bz >> 1, src = bz & 1;             // src: 0=q, 1=s
    const int o   = og * 8;

    const float* x = src ? xs : xq;
    const float *w, *bias;
    int oc;
    if (o < 128)      { oc = o;       w = w_v;               bias = b_v; }
    else if (o < 192) { oc = o - 128; w = src ? w_k2 : w_k1; bias = src ? b_k2 : b_k1; }
    else if (o < 256) { oc = o - 192; w = src ? w_q2 : w_q1; bias = src ? b_q2 : b_q1; }
    else              { oc = o - 256; w = src ? w_ts : w_tq; bias = src ? b_ts : b_tq; }

    // stage the 8x256 weight block into LDS
    for (int idx = tid; idx < 8 * 256; idx += 256) {
        int j = idx >> 8, c = idx & 255;
        wsh[j][c] = w[(size_t)(oc + j) * NCH + c];
    }
    __syncthreads();

    float acc[8];
    #pragma unroll
    for (int j = 0; j < 8; ++j) acc[j] = bias[oc + j];

    const float* xb = x + (size_t)b * NCH * NPIX + n;
    for (int c = 0; c < NCH; ++c) {
        float xv = xb[(size_t)c * NPIX];
        #pragma unroll
        for (int j = 0; j < 8; ++j)
            acc[j] += xv * wsh[j][c];
    }

    if (o < 128) {
        u16* dst = (src ? vs : vq) + ((size_t)b * CI + oc) * NPIX + n;
        #pragma unroll
        for (int j = 0; j < 8; ++j) dst[(size_t)j * NPIX] = f2bfu(acc[j]);
    } else if (o < 256) {
        u16* base = (o < 192) ? kT : qT;
        int ch = (src ? 64 : 0) + oc;
        u16* dst = base + ((size_t)b * CI + ch) * NPIX + n;
        #pragma unroll
        for (int j = 0; j < 8; ++j) dst[(size_t)j * NPIX] = f2bfu(acc[j]);
    } else {
        const float* g  = src ? g_ts  : g_tq;
        const float* be = src ? be_ts : be_tq;
        const float* mm = src ? m_ts  : m_tq;
        const float* vv = src ? v_ts  : v_tq;
        u16* dst = (src ? ts : tq) + ((size_t)b * CI + oc) * NPIX + n;
        #pragma unroll
        for (int j = 0; j < 8; ++j) {
            float inv = g[oc + j] * rsqrtf(vv[oc + j] + EPS);
            dst[(size_t)j * NPIX] = f2bfu((acc[j] - mm[oc + j]) * inv + be[oc + j]);
        }
    }
}

// =====================================================================
// Kernel 2: dual flash attention (online softmax), 64-row tiles.
//   at=0: E_s = scale * softmax_m(A[n,m]) @ v_s + ts     (out slice 2)
//   at=1: E_q = scale * softmax_j(A[j,n]) @ v_q + tq     (out slice 1)
// ws tiles are bf16 bits; fp32 accumulation; fp32 output.
// 256 threads = 16x16: thread (ty,tx) owns score rows 4ty..+3, cols
// 4tx..+3, and acc rows 4ty..+3 x channels 8tx..+7.
// =====================================================================
__global__ __launch_bounds__(256) void attn_kernel(
    const u16* __restrict__ kT, const u16* __restrict__ qT,
    const u16* __restrict__ vq, const u16* __restrict__ vs,
    const u16* __restrict__ tq, const u16* __restrict__ ts,
    const float* __restrict__ scale_p,
    float* __restrict__ out)
{
    __shared__ u16 QsL[128][68];  // [c][r]
    __shared__ u16 KsL[128][68];  // [c][m]
    __shared__ u16 VsL[64][136];  // [m][c]
    __shared__ u16 PsL[64][68];   // [m][r]

    const int tid = threadIdx.x;
    const int tx = tid & 15, ty = tid >> 4;
    const int n0 = blockIdx.x * 64;
    const int at = blockIdx.y;
    const int b  = blockIdx.z;

    const u16* Qg = at ? qT : kT;
    const u16* Kg = at ? kT : qT;
    const u16* Vg = at ? vq : vs;
    const u16* Tg = at ? tq : ts;
    float* outE   = out + (size_t)(at ? 1 : 2) * 1048576;

    const size_t boff = (size_t)b * CI * NPIX;

    // stage Q tile [c][r]
    {
        const u16* Qb = Qg + boff + n0;
        for (int idx = tid; idx < 128 * 64; idx += 256) {
            int c = idx >> 6, r = idx & 63;
            QsL[c][r] = Qb[(size_t)c * NPIX + r];
        }
    }

    float acc[4][8];
    float M[4], L[4];
    #pragma unroll
    for (int i = 0; i < 4; ++i) {
        M[i] = -INFINITY; L[i] = 0.f;
        #pragma unroll
        for (int j = 0; j < 8; ++j) acc[i][j] = 0.f;
    }

    for (int mt = 0; mt < 64; ++mt) {
        const int m0 = mt * 64;
        __syncthreads();                       // protect K/V/P reuse
        const u16* Kb = Kg + boff + m0;
        const u16* Vb = Vg + boff + m0;
        for (int idx = tid; idx < 128 * 64; idx += 256) {
            int c = idx >> 6, m = idx & 63;
            u16 kvv = Kb[(size_t)c * NPIX + m];
            u16 vvv = Vb[(size_t)c * NPIX + m];
            KsL[c][m] = kvv;
            VsL[m][c] = vvv;
        }
        __syncthreads();

        // ---- scores: S[4][4] over K=128 ----
        float sv[4][4];
        #pragma unroll
        for (int i = 0; i < 4; ++i)
            #pragma unroll
            for (int j = 0; j < 4; ++j) sv[i][j] = 0.f;

        for (int c = 0; c < 128; ++c) {
            ushort4 qu = *(const ushort4*)&QsL[c][ty * 4];
            ushort4 ku = *(const ushort4*)&KsL[c][tx * 4];
            float qa[4] = {bfu2f(qu.x), bfu2f(qu.y), bfu2f(qu.z), bfu2f(qu.w)};
            float ka[4] = {bfu2f(ku.x), bfu2f(ku.y), bfu2f(ku.z), bfu2f(ku.w)};
            #pragma unroll
            for (int i = 0; i < 4; ++i)
                #pragma unroll
                for (int j = 0; j < 4; ++j) sv[i][j] += qa[i] * ka[j];
        }

        // ---- online softmax update ----
        #pragma unroll
        for (int i = 0; i < 4; ++i) {
            float tm = fmaxf(fmaxf(sv[i][0], sv[i][1]), fmaxf(sv[i][2], sv[i][3]));
            tm = fmaxf(tm, __shfl_xor(tm, 1));
            tm = fmaxf(tm, __shfl_xor(tm, 2));
            tm = fmaxf(tm, __shfl_xor(tm, 4));
            tm = fmaxf(tm, __shfl_xor(tm, 8));
            float nm = fmaxf(M[i], tm);
            float al = __expf(M[i] - nm);
            M[i] = nm;
            float p0 = __expf(sv[i][0] - nm);
            float p1 = __expf(sv[i][1] - nm);
            float p2 = __expf(sv[i][2] - nm);
            float p3 = __expf(sv[i][3] - nm);
            float tsum = p0 + p1 + p2 + p3;
            tsum += __shfl_xor(tsum, 1);
            tsum += __shfl_xor(tsum, 2);
            tsum += __shfl_xor(tsum, 4);
            tsum += __shfl_xor(tsum, 8);
            L[i] = L[i] * al + tsum;
            #pragma unroll
            for (int j = 0; j < 8; ++j) acc[i][j] *= al;
            PsL[tx * 4 + 0][ty * 4 + i] = f2bfu(p0);
            PsL[tx * 4 + 1][ty * 4 + i] = f2bfu(p1);
            PsL[tx * 4 + 2][ty * 4 + i] = f2bfu(p2);
            PsL[tx * 4 + 3][ty * 4 + i] = f2bfu(p3);
        }
        __syncthreads();

        // ---- PV: acc[i][j] += P[r][m] * V[m][c] ----
        for (int m = 0; m < 64; ++m) {
            ushort4 pu  = *(const ushort4*)&PsL[m][ty * 4];
            ushort4 vu0 = *(const ushort4*)&VsL[m][tx * 8];
            ushort4 vu1 = *(const ushort4*)&VsL[m][tx * 8 + 4];
            float pa[4] = {bfu2f(pu.x), bfu2f(pu.y), bfu2f(pu.z), bfu2f(pu.w)};
            float va[8] = {bfu2f(vu0.x), bfu2f(vu0.y), bfu2f(vu0.z), bfu2f(vu0.w),
                           bfu2f(vu1.x), bfu2f(vu1.y), bfu2f(vu1.z), bfu2f(vu1.w)};
            #pragma unroll
            for (int i = 0; i < 4; ++i)
                #pragma unroll
                for (int j = 0; j < 8; ++j) acc[i][j] += pa[i] * va[j];
        }
    }

    // ---- epilogue: normalize, transpose through LDS, add t, store fp32 ----
    __syncthreads();
    #pragma unroll
    for (int i = 0; i < 4; ++i) {
        float inv = 1.f / L[i];
        #pragma unroll
        for (int j = 0; j < 8; ++j)
            QsL[tx * 8 + j][ty * 4 + i] = f2bfu(acc[i][j] * inv);
    }
    __syncthreads();
    float scale = *scale_p;
    const u16* Tb = Tg + boff + n0;
    float* Ob = outE + boff + n0;
    for (int idx = tid; idx < 128 * 64; idx += 256) {
        int c = idx >> 6, r = idx & 63;
        float v = scale * bfu2f(QsL[c][r]) + bfu2f(Tb[(size_t)c * NPIX + r]);
        Ob[(size_t)c * NPIX + r] = v;
    }
}

// =====================================================================
// Kernel 3: 3x3 conv (256 -> 128 ch, SAME) + BN + ReLU, fp32.
// Input = [E_q ; E_s] read from d_out slices 1 and 2.
// Block: 16-row band x 64 cols, 4 output channels; thread = 1 row x 4 cols.
// =====================================================================
__global__ __launch_bounds__(256) void conv_kernel(
    const float* __restrict__ Eq, const float* __restrict__ Es,
    const float* __restrict__ w_cat,
    const float* __restrict__ g_cat, const float* __restrict__ be_cat,
    const float* __restrict__ m_cat, const float* __restrict__ v_cat,
    float* __restrict__ out)
{
    __shared__ float xsh[18][68];
    __shared__ float wl[256 * 4 * 12];   // [ic][oo][12]

    const int tid  = threadIdx.x;
    const int cg   = tid & 15;     // col group (4 cols)
    const int lr   = tid >> 4;     // local row 0..15
    const int tile = blockIdx.x;   // 0..3
    const int o0   = blockIdx.y * 4;
    const int b    = blockIdx.z;
    const int h0   = tile * 16;

    for (int idx = tid; idx < 4 * 256 * 9; idx += 256) {
        int oo  = idx / 2304;
        int rem = idx - oo * 2304;
        int ic  = rem / 9;
        int t   = rem - ic * 9;
        wl[(ic * 4 + oo) * 12 + t] = w_cat[(size_t)o0 * 2304 + idx];
    }

    float acc[4][4];
    #pragma unroll
    for (int oo = 0; oo < 4; ++oo)
        #pragma unroll
        for (int dx = 0; dx < 4; ++dx) acc[oo][dx] = 0.f;

    for (int ic = 0; ic < 256; ++ic) {
        const float* src = (ic < 128) ? (Eq + ((size_t)b * CI + ic) * NPIX)
                                      : (Es + ((size_t)b * CI + (ic - 128)) * NPIX);
        __syncthreads();
        for (int idx = tid; idx < 18 * 66; idx += 256) {
            int r  = idx / 66, cc = idx - r * 66;
            int gh = h0 + r - 1, gw = cc - 1;
            float v = 0.f;
            if ((unsigned)gh < 64u && (unsigned)gw < 64u) v = src[gh * 64 + gw];
            xsh[r][cc] = v;
        }
        __syncthreads();

        float xr[3][6];
        #pragma unroll
        for (int r = 0; r < 3; ++r) {
            float4 a   = *(const float4*)&xsh[lr + r][cg * 4];
            float2 b2v = *(const float2*)&xsh[lr + r][cg * 4 + 4];
            xr[r][0] = a.x; xr[r][1] = a.y; xr[r][2] = a.z; xr[r][3] = a.w;
            xr[r][4] = b2v.x; xr[r][5] = b2v.y;
        }
        const float* wbase = &wl[(ic * 4) * 12];
        #pragma unroll
        for (int oo = 0; oo < 4; ++oo) {
            const float* wp = wbase + oo * 12;
            float4 w0 = *(const float4*)wp;
            float4 w1 = *(const float4*)(wp + 4);
            float  w8 = wp[8];
            #pragma unroll
            for (int dx = 0; dx < 4; ++dx) {
                acc[oo][dx] += xr[0][dx]     * w0.x + xr[0][dx + 1] * w0.y + xr[0][dx + 2] * w0.z
                             + xr[1][dx]     * w0.w + xr[1][dx + 1] * w1.x + xr[1][dx + 2] * w1.y
                             + xr[2][dx]     * w1.z + xr[2][dx + 1] * w1.w + xr[2][dx + 2] * w8;
            }
        }
    }

    const int h = h0 + lr;
    #pragma unroll
    for (int oo = 0; oo < 4; ++oo) {
        int o = o0 + oo;
        float inv = g_cat[o] * rsqrtf(v_cat[o] + EPS);
        float mm  = m_cat[o];
        float be  = be_cat[o];
        float* op = out + ((size_t)b * CI + o) * NPIX + h * 64 + cg * 4;
        #pragma unroll
        for (int dx = 0; dx < 4; ++dx) {
            float r = (acc[oo][dx] - mm) * inv + be;
            op[dx] = fmaxf(r, 0.f);
        }
    }
}

// =====================================================================
extern "C" void kernel_launch(void* const* d_in, const int* in_sizes, int n_in,
                              void* d_out, int out_size, void* d_ws, size_t ws_size,
                              hipStream_t stream)
{
    const float* q     = (const float*)d_in[0];
    const float* s     = (const float*)d_in[1];
    const float* scale = (const float*)d_in[2];
    const float* w_v   = (const float*)d_in[3];
    const float* b_v   = (const float*)d_in[4];
    const float* w_k1  = (const float*)d_in[5];
    const float* b_k1  = (const float*)d_in[6];
    const float* w_q1  = (const float*)d_in[7];
    const float* b_q1  = (const float*)d_in[8];
    const float* w_k2  = (const float*)d_in[9];
    const float* b_k2  = (const float*)d_in[10];
    const float* w_q2  = (const float*)d_in[11];
    const float* b_q2  = (const float*)d_in[12];
    const float* w_ts  = (const float*)d_in[13];
    const float* b_ts  = (const float*)d_in[14];
    const float* g_ts  = (const float*)d_in[15];
    const float* be_ts = (const float*)d_in[16];
    const float* m_ts  = (const float*)d_in[17];
    const float* v_ts  = (const float*)d_in[18];
    const float* w_tq  = (const float*)d_in[19];
    const float* b_tq  = (const float*)d_in[20];
    const float* g_tq  = (const float*)d_in[21];
    const float* be_tq = (const float*)d_in[22];
    const float* m_tq  = (const float*)d_in[23];
    const float* v_tq  = (const float*)d_in[24];
    const float* w_cat = (const float*)d_in[25];
    const float* g_cat = (const float*)d_in[26];
    const float* be_cat= (const float*)d_in[27];
    const float* m_cat = (const float*)d_in[28];
    const float* v_cat = (const float*)d_in[29];

    float* out = (float*)d_out;
    u16* ws = (u16*)d_ws;
    const size_t SZ = (size_t)2 * CI * NPIX;   // 1,048,576 elements per buffer
    u16* kT = ws;
    u16* qT = kT + SZ;
    u16* vq = qT + SZ;
    u16* vs = vq + SZ;
    u16* tq = vs + SZ;
    u16* ts = tq + SZ;

    dim3 blk(256);
    hipLaunchKernelGGL(proj_kernel, dim3(16, 48, 4), blk, 0, stream,
                       q, s, w_v, b_v, w_k1, b_k1, w_q1, b_q1, w_k2, b_k2, w_q2, b_q2,
                       w_ts, b_ts, g_ts, be_ts, m_ts, v_ts,
                       w_tq, b_tq, g_tq, be_tq, m_tq, v_tq,
                       kT, qT, vq, vs, tq, ts);

    hipLaunchKernelGGL(attn_kernel, dim3(64, 2, 2), blk, 0, stream,
                       kT, qT, vq, vs, tq, ts, scale, out);

    hipLaunchKernelGGL(conv_kernel, dim3(4, 32, 2), blk, 0, stream,
                       out + 1048576, out + 2097152,
                       w_cat, g_cat, be_cat, m_cat, v_cat, out);
}

// Round 3
// 898.731 us; speedup vs baseline: 1.7718x; 1.7718x over previous
//
#include <hip/hip_runtime.h>
#include <hip/hip_bf16.h>

#define NPIX 4096   // H*W
#define NCH  256    // input channels
#define CI   128    // inter channels
#define EPS  1e-5f

typedef unsigned short u16;
typedef __attribute__((ext_vector_type(8))) short short8;   // 8 bf16 (4 VGPRs)
typedef __attribute__((ext_vector_type(4))) float f32x4;    // MFMA C/D

// ---------- bf16 bit helpers ----------
__device__ __forceinline__ float bfu2f(u16 u) {
    union { unsigned int i; float f; } x; x.i = ((unsigned int)u) << 16; return x.f;
}
__device__ __forceinline__ u16 f2bfu(float f) {
    union { float ff; unsigned int i; } x; x.ff = f;
    unsigned int r = x.i + 0x7FFFu + ((x.i >> 16) & 1u);
    return (u16)(r >> 16);
}

// =====================================================================
// Kernel 1: all 1x1 convolutions (+BN for t-branches). fp32 in, bf16 bits
// out to ws. Layouts: kT,qT = [b][n][c] (for MFMA fragment loads);
// vq,vs,tq,ts = [b][c][n].
// =====================================================================
__global__ __launch_bounds__(256) void proj_kernel(
    const float* __restrict__ xq, const float* __restrict__ xs,
    const float* __restrict__ w_v,  const float* __restrict__ b_v,
    const float* __restrict__ w_k1, const float* __restrict__ b_k1,
    const float* __restrict__ w_q1, const float* __restrict__ b_q1,
    const float* __restrict__ w_k2, const float* __restrict__ b_k2,
    const float* __restrict__ w_q2, const float* __restrict__ b_q2,
    const float* __restrict__ w_ts, const float* __restrict__ b_ts,
    const float* __restrict__ g_ts, const float* __restrict__ be_ts,
    const float* __restrict__ m_ts, const float* __restrict__ v_ts,
    const float* __restrict__ w_tq, const float* __restrict__ b_tq,
    const float* __restrict__ g_tq, const float* __restrict__ be_tq,
    const float* __restrict__ m_tq, const float* __restrict__ v_tq,
    u16* __restrict__ kT, u16* __restrict__ qT,
    u16* __restrict__ vq, u16* __restrict__ vs,
    u16* __restrict__ tq, u16* __restrict__ ts)
{
    __shared__ float wsh[8][256];

    const int tid = threadIdx.x;
    const int n   = blockIdx.x * 256 + tid;            // pixel
    const int og  = blockIdx.y;                        // 0..47  (o = og*8)
    const int bz  = blockIdx.z;                        // 0..3
    const int b   = bz >> 1, src = bz & 1;             // src: 0=q, 1=s
    const int o   = og * 8;

    const float* x = src ? xs : xq;
    const float *w, *bias;
    int oc;
    if (o < 128)      { oc = o;       w = w_v;               bias = b_v; }
    else if (o < 192) { oc = o - 128; w = src ? w_k2 : w_k1; bias = src ? b_k2 : b_k1; }
    else if (o < 256) { oc = o - 192; w = src ? w_q2 : w_q1; bias = src ? b_q2 : b_q1; }
    else              { oc = o - 256; w = src ? w_ts : w_tq; bias = src ? b_ts : b_tq; }

    for (int idx = tid; idx < 8 * 256; idx += 256) {
        int j = idx >> 8, c = idx & 255;
        wsh[j][c] = w[(size_t)(oc + j) * NCH + c];
    }
    __syncthreads();

    float acc[8];
    #pragma unroll
    for (int j = 0; j < 8; ++j) acc[j] = bias[oc + j];

    const float* xb = x + (size_t)b * NCH * NPIX + n;
    for (int c = 0; c < NCH; ++c) {
        float xv = xb[(size_t)c * NPIX];
        #pragma unroll
        for (int j = 0; j < 8; ++j)
            acc[j] += xv * wsh[j][c];
    }

    if (o < 128) {
        u16* dst = (src ? vs : vq) + ((size_t)b * CI + oc) * NPIX + n;
        #pragma unroll
        for (int j = 0; j < 8; ++j) dst[(size_t)j * NPIX] = f2bfu(acc[j]);
    } else if (o < 256) {
        u16* base = (o < 192) ? kT : qT;
        int ch = (src ? 64 : 0) + oc;
        union { u16 u[8]; uint4 v; } pk;
        #pragma unroll
        for (int j = 0; j < 8; ++j) pk.u[j] = f2bfu(acc[j]);
        *(uint4*)(base + ((size_t)b * NPIX + n) * CI + ch) = pk.v;
    } else {
        const float* g  = src ? g_ts  : g_tq;
        const float* be = src ? be_ts : be_tq;
        const float* mm = src ? m_ts  : m_tq;
        const float* vv = src ? v_ts  : v_tq;
        u16* dst = (src ? ts : tq) + ((size_t)b * CI + oc) * NPIX + n;
        #pragma unroll
        for (int j = 0; j < 8; ++j) {
            float inv = g[oc + j] * rsqrtf(vv[oc + j] + EPS);
            dst[(size_t)j * NPIX] = f2bfu((acc[j] - mm[oc + j]) * inv + be[oc + j]);
        }
    }
}

// =====================================================================
// Kernel 2: dual flash attention with MFMA (bf16 16x16x32).
//   at=0: E_s = scale * softmax_m(A[n,m]) @ v_s + ts   (out slice 2)
//   at=1: E_q = scale * softmax_j(A[j,n]) @ v_q + tq   (out slice 1)
// Block = 256 threads = 4 waves; BR=64 q-rows; m-tiles of 64.
// Wave w computes the 16-row strip [w*16, w*16+16).
// LDS (u16 units):
//   Qs  [64][136]  off 0       (A-operand rows, stride 136)
//   Ks  [64][136]  off 8704    (B-operand rows for S)
//   Vt  [128][72]  off 17408   (B-operand rows for PV: Vt[c][m])
//   Ps  [64][72]   off 26624   (P round-trip C-layout -> A-layout)
//   epilogue reuses [0..17408) as float Of[128][68]
// =====================================================================
#define QS_OFF 0
#define KS_OFF 8704
#define VT_OFF 17408
#define PS_OFF 26624
#define SMEM_U16 31232

__global__ __launch_bounds__(256) void attn_kernel(
    const u16* __restrict__ kT, const u16* __restrict__ qT,
    const u16* __restrict__ vq, const u16* __restrict__ vs,
    const u16* __restrict__ tq, const u16* __restrict__ ts,
    const float* __restrict__ scale_p,
    float* __restrict__ out)
{
    __shared__ u16 smem[SMEM_U16];
    u16* Qs = smem + QS_OFF;
    u16* Ks = smem + KS_OFF;
    u16* Vt = smem + VT_OFF;
    u16* Ps = smem + PS_OFF;

    const int tid  = threadIdx.x;
    const int lane = tid & 63;
    const int wid  = tid >> 6;          // 0..3
    const int l16  = lane & 15;
    const int quad = lane >> 4;         // 0..3
    const int strip = wid * 16;

    const int n0 = blockIdx.x * 64;
    const int at = blockIdx.y;
    const int b  = blockIdx.z;

    const u16* Qg = at ? qT : kT;       // [b][n][c]
    const u16* Kg = at ? kT : qT;       // [b][n][c]
    const u16* Vg = at ? vq : vs;       // [b][c][n]
    const u16* Tg = at ? tq : ts;       // [b][c][n]
    float* outE   = out + (size_t)(at ? 1 : 2) * 1048576;

    // ---- stage Q tile: Qs[r][c], 16B vector loads ----
    {
        const u16* Qb = Qg + ((size_t)b * NPIX + n0) * CI;
        #pragma unroll
        for (int k = 0; k < 4; ++k) {
            int idx = tid + k * 256;            // 0..1023
            int row = idx >> 4, seg = idx & 15;
            *(uint4*)&Qs[row * 136 + seg * 8] =
                *(const uint4*)&Qb[(size_t)row * CI + seg * 8];
        }
    }
    __syncthreads();

    // A-fragments of Q (persist across m-loop)
    short8 af[4];
    #pragma unroll
    for (int kc = 0; kc < 4; ++kc)
        af[kc] = *(const short8*)&Qs[(strip + l16) * 136 + kc * 32 + quad * 8];

    f32x4 o[8];
    #pragma unroll
    for (int ct = 0; ct < 8; ++ct) o[ct] = (f32x4){0.f, 0.f, 0.f, 0.f};
    float M[4], L[4];
    #pragma unroll
    for (int r = 0; r < 4; ++r) { M[r] = -INFINITY; L[r] = 0.f; }

    const u16* KgB = Kg + (size_t)b * NPIX * CI;
    const u16* VgB = Vg + (size_t)b * CI * NPIX;

    for (int mt = 0; mt < 64; ++mt) {
        const int m0 = mt * 64;
        __syncthreads();   // Ps/Vt from prev iter fully consumed
        // ---- stage K tile (rows [n][c]) and V tile (Vt[c][m]) ----
        {
            const u16* Kb = KgB + (size_t)m0 * CI;
            const u16* Vb = VgB + m0;
            #pragma unroll
            for (int k = 0; k < 4; ++k) {
                int idx = tid + k * 256;
                int row = idx >> 4, seg = idx & 15;
                *(uint4*)&Ks[row * 136 + seg * 8] =
                    *(const uint4*)&Kb[(size_t)row * CI + seg * 8];
            }
            #pragma unroll
            for (int k = 0; k < 4; ++k) {
                int idx = tid + k * 256;
                int c = idx >> 3, seg = idx & 7;
                *(uint4*)&Vt[c * 72 + seg * 8] =
                    *(const uint4*)&Vb[(size_t)c * NPIX + seg * 8];
            }
        }
        __syncthreads();

        // ---- S = Q K^T : 4 column tiles x 4 k-chunks ----
        f32x4 sv[4];
        #pragma unroll
        for (int ct = 0; ct < 4; ++ct) {
            f32x4 c = (f32x4){0.f, 0.f, 0.f, 0.f};
            #pragma unroll
            for (int kc = 0; kc < 4; ++kc) {
                short8 bf = *(const short8*)&Ks[(ct * 16 + l16) * 136 + kc * 32 + quad * 8];
                c = __builtin_amdgcn_mfma_f32_16x16x32_bf16(af[kc], bf, c, 0, 0, 0);
            }
            sv[ct] = c;
        }

        // ---- online softmax (rows = strip + quad*4 + r) ----
        #pragma unroll
        for (int r = 0; r < 4; ++r) {
            float tm = fmaxf(fmaxf(sv[0][r], sv[1][r]), fmaxf(sv[2][r], sv[3][r]));
            tm = fmaxf(tm, __shfl_xor(tm, 1));
            tm = fmaxf(tm, __shfl_xor(tm, 2));
            tm = fmaxf(tm, __shfl_xor(tm, 4));
            tm = fmaxf(tm, __shfl_xor(tm, 8));
            float nm = fmaxf(M[r], tm);
            float al = __expf(M[r] - nm);
            M[r] = nm;
            float p0 = __expf(sv[0][r] - nm);
            float p1 = __expf(sv[1][r] - nm);
            float p2 = __expf(sv[2][r] - nm);
            float p3 = __expf(sv[3][r] - nm);
            float tsum = p0 + p1 + p2 + p3;
            tsum += __shfl_xor(tsum, 1);
            tsum += __shfl_xor(tsum, 2);
            tsum += __shfl_xor(tsum, 4);
            tsum += __shfl_xor(tsum, 8);
            L[r] = L[r] * al + tsum;
            #pragma unroll
            for (int ct = 0; ct < 8; ++ct) {
                o[ct][r] *= al;
            }
            int prow = strip + quad * 4 + r;
            Ps[prow * 72 + 0 * 16 + l16] = f2bfu(p0);
            Ps[prow * 72 + 1 * 16 + l16] = f2bfu(p1);
            Ps[prow * 72 + 2 * 16 + l16] = f2bfu(p2);
            Ps[prow * 72 + 3 * 16 + l16] = f2bfu(p3);
        }
        __syncthreads();

        // ---- PV: o[64][128] += P[64][64] @ V[64][128] ----
        short8 ap[2];
        #pragma unroll
        for (int kc = 0; kc < 2; ++kc)
            ap[kc] = *(const short8*)&Ps[(strip + l16) * 72 + kc * 32 + quad * 8];
        #pragma unroll
        for (int ct = 0; ct < 8; ++ct) {
            #pragma unroll
            for (int kc = 0; kc < 2; ++kc) {
                short8 bv = *(const short8*)&Vt[(ct * 16 + l16) * 72 + kc * 32 + quad * 8];
                o[ct] = __builtin_amdgcn_mfma_f32_16x16x32_bf16(ap[kc], bv, o[ct], 0, 0, 0);
            }
        }
    }

    // ---- epilogue: normalize, transpose via LDS (f32), add t, store ----
    __syncthreads();
    float* Of = (float*)smem;           // [128][68] floats, reuses Qs+Ks
    #pragma unroll
    for (int r = 0; r < 4; ++r) {
        float inv = 1.f / L[r];
        int row = strip + quad * 4 + r;
        #pragma unroll
        for (int ct = 0; ct < 8; ++ct)
            Of[(ct * 16 + l16) * 68 + row] = o[ct][r] * inv;
    }
    __syncthreads();
    float scale = *scale_p;
    const u16* Tb = Tg + (size_t)b * CI * NPIX + n0;
    float* Ob = outE + (size_t)b * CI * NPIX + n0;
    for (int idx = tid; idx < 128 * 64; idx += 256) {
        int c = idx >> 6, r = idx & 63;
        float v = scale * Of[c * 68 + r] + bfu2f(Tb[(size_t)c * NPIX + r]);
        Ob[(size_t)c * NPIX + r] = v;
    }
}

// =====================================================================
// Kernel 3: 3x3 conv (256 -> 128 ch, SAME) + BN + ReLU, fp32 (unchanged).
// =====================================================================
__global__ __launch_bounds__(256) void conv_kernel(
    const float* __restrict__ Eq, const float* __restrict__ Es,
    const float* __restrict__ w_cat,
    const float* __restrict__ g_cat, const float* __restrict__ be_cat,
    const float* __restrict__ m_cat, const float* __restrict__ v_cat,
    float* __restrict__ out)
{
    __shared__ float xsh[18][68];
    __shared__ float wl[256 * 4 * 12];   // [ic][oo][12]

    const int tid  = threadIdx.x;
    const int cg   = tid & 15;
    const int lr   = tid >> 4;
    const int tile = blockIdx.x;
    const int o0   = blockIdx.y * 4;
    const int b    = blockIdx.z;
    const int h0   = tile * 16;

    for (int idx = tid; idx < 4 * 256 * 9; idx += 256) {
        int oo  = idx / 2304;
        int rem = idx - oo * 2304;
        int ic  = rem / 9;
        int t   = rem - ic * 9;
        wl[(ic * 4 + oo) * 12 + t] = w_cat[(size_t)o0 * 2304 + idx];
    }

    float acc[4][4];
    #pragma unroll
    for (int oo = 0; oo < 4; ++oo)
        #pragma unroll
        for (int dx = 0; dx < 4; ++dx) acc[oo][dx] = 0.f;

    for (int ic = 0; ic < 256; ++ic) {
        const float* src = (ic < 128) ? (Eq + ((size_t)b * CI + ic) * NPIX)
                                      : (Es + ((size_t)b * CI + (ic - 128)) * NPIX);
        __syncthreads();
        for (int idx = tid; idx < 18 * 66; idx += 256) {
            int r  = idx / 66, cc = idx - r * 66;
            int gh = h0 + r - 1, gw = cc - 1;
            float v = 0.f;
            if ((unsigned)gh < 64u && (unsigned)gw < 64u) v = src[gh * 64 + gw];
            xsh[r][cc] = v;
        }
        __syncthreads();

        float xr[3][6];
        #pragma unroll
        for (int r = 0; r < 3; ++r) {
            float4 a   = *(const float4*)&xsh[lr + r][cg * 4];
            float2 b2v = *(const float2*)&xsh[lr + r][cg * 4 + 4];
            xr[r][0] = a.x; xr[r][1] = a.y; xr[r][2] = a.z; xr[r][3] = a.w;
            xr[r][4] = b2v.x; xr[r][5] = b2v.y;
        }
        const float* wbase = &wl[(ic * 4) * 12];
        #pragma unroll
        for (int oo = 0; oo < 4; ++oo) {
            const float* wp = wbase + oo * 12;
            float4 w0 = *(const float4*)wp;
            float4 w1 = *(const float4*)(wp + 4);
            float  w8 = wp[8];
            #pragma unroll
            for (int dx = 0; dx < 4; ++dx) {
                acc[oo][dx] += xr[0][dx]     * w0.x + xr[0][dx + 1] * w0.y + xr[0][dx + 2] * w0.z
                             + xr[1][dx]     * w0.w + xr[1][dx + 1] * w1.x + xr[1][dx + 2] * w1.y
                             + xr[2][dx]     * w1.z + xr[2][dx + 1] * w1.w + xr[2][dx + 2] * w8;
            }
        }
    }

    const int h = h0 + lr;
    #pragma unroll
    for (int oo = 0; oo < 4; ++oo) {
        int o = o0 + oo;
        float inv = g_cat[o] * rsqrtf(v_cat[o] + EPS);
        float mm  = m_cat[o];
        float be  = be_cat[o];
        float* op = out + ((size_t)b * CI + o) * NPIX + h * 64 + cg * 4;
        #pragma unroll
        for (int dx = 0; dx < 4; ++dx) {
            float r = (acc[oo][dx] - mm) * inv + be;
            op[dx] = fmaxf(r, 0.f);
        }
    }
}

// =====================================================================
extern "C" void kernel_launch(void* const* d_in, const int* in_sizes, int n_in,
                              void* d_out, int out_size, void* d_ws, size_t ws_size,
                              hipStream_t stream)
{
    const float* q     = (const float*)d_in[0];
    const float* s     = (const float*)d_in[1];
    const float* scale = (const float*)d_in[2];
    const float* w_v   = (const float*)d_in[3];
    const float* b_v   = (const float*)d_in[4];
    const float* w_k1  = (const float*)d_in[5];
    const float* b_k1  = (const float*)d_in[6];
    const float* w_q1  = (const float*)d_in[7];
    const float* b_q1  = (const float*)d_in[8];
    const float* w_k2  = (const float*)d_in[9];
    const float* b_k2  = (const float*)d_in[10];
    const float* w_q2  = (const float*)d_in[11];
    const float* b_q2  = (const float*)d_in[12];
    const float* w_ts  = (const float*)d_in[13];
    const float* b_ts  = (const float*)d_in[14];
    const float* g_ts  = (const float*)d_in[15];
    const float* be_ts = (const float*)d_in[16];
    const float* m_ts  = (const float*)d_in[17];
    const float* v_ts  = (const float*)d_in[18];
    const float* w_tq  = (const float*)d_in[19];
    const float* b_tq  = (const float*)d_in[20];
    const float* g_tq  = (const float*)d_in[21];
    const float* be_tq = (const float*)d_in[22];
    const float* m_tq  = (const float*)d_in[23];
    const float* v_tq  = (const float*)d_in[24];
    const float* w_cat = (const float*)d_in[25];
    const float* g_cat = (const float*)d_in[26];
    const float* be_cat= (const float*)d_in[27];
    const float* m_cat = (const float*)d_in[28];
    const float* v_cat = (const float*)d_in[29];

    float* out = (float*)d_out;
    u16* ws = (u16*)d_ws;
    const size_t SZ = (size_t)2 * CI * NPIX;   // 1,048,576 elements per buffer
    u16* kT = ws;            // [b][n][c]
    u16* qT = kT + SZ;       // [b][n][c]
    u16* vq = qT + SZ;       // [b][c][n]
    u16* vs = vq + SZ;       // [b][c][n]
    u16* tq = vs + SZ;       // [b][c][n]
    u16* ts = tq + SZ;       // [b][c][n]

    dim3 blk(256);
    hipLaunchKernelGGL(proj_kernel, dim3(16, 48, 4), blk, 0, stream,
                       q, s, w_v, b_v, w_k1, b_k1, w_q1, b_q1, w_k2, b_k2, w_q2, b_q2,
                       w_ts, b_ts, g_ts, be_ts, m_ts, v_ts,
                       w_tq, b_tq, g_tq, be_tq, m_tq, v_tq,
                       kT, qT, vq, vs, tq, ts);

    hipLaunchKernelGGL(attn_kernel, dim3(64, 2, 2), blk, 0, stream,
                       kT, qT, vq, vs, tq, ts, scale, out);

    hipLaunchKernelGGL(conv_kernel, dim3(4, 32, 2), blk, 0, stream,
                       out + 1048576, out + 2097152,
                       w_cat, g_cat, be_cat, m_cat, v_cat, out);
}

// Round 4
// 367.877 us; speedup vs baseline: 4.3286x; 2.4430x over previous
//
#include <hip/hip_runtime.h>
#include <hip/hip_bf16.h>

#define NPIX 4096   // H*W
#define NCH  256    // input channels
#define CI   128    // inter channels
#define EPS  1e-5f

typedef unsigned short u16;
typedef __attribute__((ext_vector_type(8))) short short8;   // 8 bf16 (4 VGPRs)
typedef __attribute__((ext_vector_type(4))) float f32x4;    // MFMA C/D

// ---------- bf16 bit helpers ----------
__device__ __forceinline__ float bfu2f(u16 u) {
    union { unsigned int i; float f; } x; x.i = ((unsigned int)u) << 16; return x.f;
}
__device__ __forceinline__ u16 f2bfu(float f) {
    union { float ff; unsigned int i; } x; x.ff = f;
    unsigned int r = x.i + 0x7FFFu + ((x.i >> 16) & 1u);
    return (u16)(r >> 16);
}

// =====================================================================
// Kernel 1: all 1x1 convolutions (+BN for t-branches). fp32 in, bf16 bits
// out to ws. Layouts: kT,qT = [b][n][c]; vq,vs,tq,ts = [b][c][n].
// =====================================================================
__global__ __launch_bounds__(256) void proj_kernel(
    const float* __restrict__ xq, const float* __restrict__ xs,
    const float* __restrict__ w_v,  const float* __restrict__ b_v,
    const float* __restrict__ w_k1, const float* __restrict__ b_k1,
    const float* __restrict__ w_q1, const float* __restrict__ b_q1,
    const float* __restrict__ w_k2, const float* __restrict__ b_k2,
    const float* __restrict__ w_q2, const float* __restrict__ b_q2,
    const float* __restrict__ w_ts, const float* __restrict__ b_ts,
    const float* __restrict__ g_ts, const float* __restrict__ be_ts,
    const float* __restrict__ m_ts, const float* __restrict__ v_ts,
    const float* __restrict__ w_tq, const float* __restrict__ b_tq,
    const float* __restrict__ g_tq, const float* __restrict__ be_tq,
    const float* __restrict__ m_tq, const float* __restrict__ v_tq,
    u16* __restrict__ kT, u16* __restrict__ qT,
    u16* __restrict__ vq, u16* __restrict__ vs,
    u16* __restrict__ tq, u16* __restrict__ ts)
{
    __shared__ float wsh[8][256];

    const int tid = threadIdx.x;
    const int n   = blockIdx.x * 256 + tid;            // pixel
    const int og  = blockIdx.y;                        // 0..47  (o = og*8)
    const int bz  = blockIdx.z;                        // 0..3
    const int b   = bz >> 1, src = bz & 1;             // src: 0=q, 1=s
    const int o   = og * 8;

    const float* x = src ? xs : xq;
    const float *w, *bias;
    int oc;
    if (o < 128)      { oc = o;       w = w_v;               bias = b_v; }
    else if (o < 192) { oc = o - 128; w = src ? w_k2 : w_k1; bias = src ? b_k2 : b_k1; }
    else if (o < 256) { oc = o - 192; w = src ? w_q2 : w_q1; bias = src ? b_q2 : b_q1; }
    else              { oc = o - 256; w = src ? w_ts : w_tq; bias = src ? b_ts : b_tq; }

    for (int idx = tid; idx < 8 * 256; idx += 256) {
        int j = idx >> 8, c = idx & 255;
        wsh[j][c] = w[(size_t)(oc + j) * NCH + c];
    }
    __syncthreads();

    float acc[8];
    #pragma unroll
    for (int j = 0; j < 8; ++j) acc[j] = bias[oc + j];

    const float* xb = x + (size_t)b * NCH * NPIX + n;
    for (int c = 0; c < NCH; ++c) {
        float xv = xb[(size_t)c * NPIX];
        #pragma unroll
        for (int j = 0; j < 8; ++j)
            acc[j] += xv * wsh[j][c];
    }

    if (o < 128) {
        u16* dst = (src ? vs : vq) + ((size_t)b * CI + oc) * NPIX + n;
        #pragma unroll
        for (int j = 0; j < 8; ++j) dst[(size_t)j * NPIX] = f2bfu(acc[j]);
    } else if (o < 256) {
        u16* base = (o < 192) ? kT : qT;
        int ch = (src ? 64 : 0) + oc;
        union { u16 u[8]; uint4 v; } pk;
        #pragma unroll
        for (int j = 0; j < 8; ++j) pk.u[j] = f2bfu(acc[j]);
        *(uint4*)(base + ((size_t)b * NPIX + n) * CI + ch) = pk.v;
    } else {
        const float* g  = src ? g_ts  : g_tq;
        const float* be = src ? be_ts : be_tq;
        const float* mm = src ? m_ts  : m_tq;
        const float* vv = src ? v_ts  : v_tq;
        u16* dst = (src ? ts : tq) + ((size_t)b * CI + oc) * NPIX + n;
        #pragma unroll
        for (int j = 0; j < 8; ++j) {
            float inv = g[oc + j] * rsqrtf(vv[oc + j] + EPS);
            dst[(size_t)j * NPIX] = f2bfu((acc[j] - mm[oc + j]) * inv + be[oc + j]);
        }
    }
}

// =====================================================================
// Kernel 1b: transpose conv weights to bf16 wT[co][tap][ic].
// w_cat is [co][ic][kh][kw] fp32.
// =====================================================================
__global__ __launch_bounds__(256) void wprep_kernel(
    const float* __restrict__ w_cat, u16* __restrict__ wT)
{
    const int co = blockIdx.x;
    const float* srcb = w_cat + (size_t)co * 2304;
    u16* dstb = wT + (size_t)co * 2304;
    for (int t = threadIdx.x; t < 2304; t += 256) {
        int ic = t / 9, tap = t - ic * 9;
        dstb[tap * 256 + ic] = f2bfu(srcb[t]);
    }
}

// =====================================================================
// Kernel 2: dual flash attention with MFMA (bf16 16x16x32).
// Adds a bf16 copy of E to ws in [b][pixel][ch] layout (Ebf) for conv:
//   ch 0..127 = E_q (at=1), ch 128..255 = E_s (at=0).
// =====================================================================
#define QS_OFF 0
#define KS_OFF 8704
#define VT_OFF 17408
#define PS_OFF 26624
#define SMEM_U16 31232

__global__ __launch_bounds__(256) void attn_kernel(
    const u16* __restrict__ kT, const u16* __restrict__ qT,
    const u16* __restrict__ vq, const u16* __restrict__ vs,
    const u16* __restrict__ tq, const u16* __restrict__ ts,
    const float* __restrict__ scale_p,
    float* __restrict__ out, u16* __restrict__ Ebf)
{
    __shared__ u16 smem[SMEM_U16];
    u16* Qs = smem + QS_OFF;
    u16* Ks = smem + KS_OFF;
    u16* Vt = smem + VT_OFF;
    u16* Ps = smem + PS_OFF;

    const int tid  = threadIdx.x;
    const int lane = tid & 63;
    const int wid  = tid >> 6;          // 0..3
    const int l16  = lane & 15;
    const int quad = lane >> 4;         // 0..3
    const int strip = wid * 16;

    const int n0 = blockIdx.x * 64;
    const int at = blockIdx.y;
    const int b  = blockIdx.z;

    const u16* Qg = at ? qT : kT;       // [b][n][c]
    const u16* Kg = at ? kT : qT;       // [b][n][c]
    const u16* Vg = at ? vq : vs;       // [b][c][n]
    const u16* Tg = at ? tq : ts;       // [b][c][n]
    float* outE   = out + (size_t)(at ? 1 : 2) * 1048576;
    const int ch0 = at ? 0 : 128;

    // ---- stage Q tile: Qs[r][c] ----
    {
        const u16* Qb = Qg + ((size_t)b * NPIX + n0) * CI;
        #pragma unroll
        for (int k = 0; k < 4; ++k) {
            int idx = tid + k * 256;
            int row = idx >> 4, seg = idx & 15;
            *(uint4*)&Qs[row * 136 + seg * 8] =
                *(const uint4*)&Qb[(size_t)row * CI + seg * 8];
        }
    }
    __syncthreads();

    short8 af[4];
    #pragma unroll
    for (int kc = 0; kc < 4; ++kc)
        af[kc] = *(const short8*)&Qs[(strip + l16) * 136 + kc * 32 + quad * 8];

    f32x4 o[8];
    #pragma unroll
    for (int ct = 0; ct < 8; ++ct) o[ct] = (f32x4){0.f, 0.f, 0.f, 0.f};
    float M[4], L[4];
    #pragma unroll
    for (int r = 0; r < 4; ++r) { M[r] = -INFINITY; L[r] = 0.f; }

    const u16* KgB = Kg + (size_t)b * NPIX * CI;
    const u16* VgB = Vg + (size_t)b * CI * NPIX;

    for (int mt = 0; mt < 64; ++mt) {
        const int m0 = mt * 64;
        __syncthreads();
        {
            const u16* Kb = KgB + (size_t)m0 * CI;
            const u16* Vb = VgB + m0;
            #pragma unroll
            for (int k = 0; k < 4; ++k) {
                int idx = tid + k * 256;
                int row = idx >> 4, seg = idx & 15;
                *(uint4*)&Ks[row * 136 + seg * 8] =
                    *(const uint4*)&Kb[(size_t)row * CI + seg * 8];
            }
            #pragma unroll
            for (int k = 0; k < 4; ++k) {
                int idx = tid + k * 256;
                int c = idx >> 3, seg = idx & 7;
                *(uint4*)&Vt[c * 72 + seg * 8] =
                    *(const uint4*)&Vb[(size_t)c * NPIX + seg * 8];
            }
        }
        __syncthreads();

        f32x4 sv[4];
        #pragma unroll
        for (int ct = 0; ct < 4; ++ct) {
            f32x4 c = (f32x4){0.f, 0.f, 0.f, 0.f};
            #pragma unroll
            for (int kc = 0; kc < 4; ++kc) {
                short8 bf = *(const short8*)&Ks[(ct * 16 + l16) * 136 + kc * 32 + quad * 8];
                c = __builtin_amdgcn_mfma_f32_16x16x32_bf16(af[kc], bf, c, 0, 0, 0);
            }
            sv[ct] = c;
        }

        #pragma unroll
        for (int r = 0; r < 4; ++r) {
            float tm = fmaxf(fmaxf(sv[0][r], sv[1][r]), fmaxf(sv[2][r], sv[3][r]));
            tm = fmaxf(tm, __shfl_xor(tm, 1));
            tm = fmaxf(tm, __shfl_xor(tm, 2));
            tm = fmaxf(tm, __shfl_xor(tm, 4));
            tm = fmaxf(tm, __shfl_xor(tm, 8));
            float nm = fmaxf(M[r], tm);
            float al = __expf(M[r] - nm);
            M[r] = nm;
            float p0 = __expf(sv[0][r] - nm);
            float p1 = __expf(sv[1][r] - nm);
            float p2 = __expf(sv[2][r] - nm);
            float p3 = __expf(sv[3][r] - nm);
            float tsum = p0 + p1 + p2 + p3;
            tsum += __shfl_xor(tsum, 1);
            tsum += __shfl_xor(tsum, 2);
            tsum += __shfl_xor(tsum, 4);
            tsum += __shfl_xor(tsum, 8);
            L[r] = L[r] * al + tsum;
            #pragma unroll
            for (int ct = 0; ct < 8; ++ct) o[ct][r] *= al;
            int prow = strip + quad * 4 + r;
            Ps[prow * 72 + 0 * 16 + l16] = f2bfu(p0);
            Ps[prow * 72 + 1 * 16 + l16] = f2bfu(p1);
            Ps[prow * 72 + 2 * 16 + l16] = f2bfu(p2);
            Ps[prow * 72 + 3 * 16 + l16] = f2bfu(p3);
        }
        __syncthreads();

        short8 ap[2];
        #pragma unroll
        for (int kc = 0; kc < 2; ++kc)
            ap[kc] = *(const short8*)&Ps[(strip + l16) * 72 + kc * 32 + quad * 8];
        #pragma unroll
        for (int ct = 0; ct < 8; ++ct) {
            #pragma unroll
            for (int kc = 0; kc < 2; ++kc) {
                short8 bv = *(const short8*)&Vt[(ct * 16 + l16) * 72 + kc * 32 + quad * 8];
                o[ct] = __builtin_amdgcn_mfma_f32_16x16x32_bf16(ap[kc], bv, o[ct], 0, 0, 0);
            }
        }
    }

    // ---- epilogue ----
    __syncthreads();
    float* Of = (float*)smem;           // [128][68] floats
    #pragma unroll
    for (int r = 0; r < 4; ++r) {
        float inv = 1.f / L[r];
        int row = strip + quad * 4 + r;
        #pragma unroll
        for (int ct = 0; ct < 8; ++ct)
            Of[(ct * 16 + l16) * 68 + row] = o[ct][r] * inv;
    }
    __syncthreads();
    float scale = *scale_p;
    const u16* Tb = Tg + (size_t)b * CI * NPIX + n0;
    float* Ob = outE + (size_t)b * CI * NPIX + n0;
    for (int idx = tid; idx < 128 * 64; idx += 256) {
        int c = idx >> 6, r = idx & 63;
        float v = scale * Of[c * 68 + r] + bfu2f(Tb[(size_t)c * NPIX + r]);
        Ob[(size_t)c * NPIX + r] = v;
        Ebf[((size_t)b * NPIX + n0 + r) * NCH + ch0 + c] = f2bfu(v);
    }
}

// =====================================================================
// Kernel 3: 3x3 conv as MFMA implicit GEMM + BN + ReLU.
// M = 64 out-ch (block half), N = 64 pixels (one image row), K = 9*256.
// k-chunk = 32 ic at one tap. A from global wT (L2), B from LDS im2col.
// Block: 4 waves, wave w: co tiles {2(w>>1),2(w>>1)+1} x px tiles
// {2(w&1),2(w&1)+1}. Grid (64 rows, 2 co-halves, 2 batches) = 256 blocks.
// =====================================================================
#define XT_STR 40   // u16 stride per x (80 B = 20 dwords, only 2-way bank alias)

__global__ __launch_bounds__(256) void conv_kernel(
    const u16* __restrict__ Ebf,   // [b][pix][256]
    const u16* __restrict__ wT,    // [co][tap][ic]
    const float* __restrict__ g_cat, const float* __restrict__ be_cat,
    const float* __restrict__ m_cat, const float* __restrict__ v_cat,
    float* __restrict__ out)
{
    __shared__ u16 Xt[3 * 66 * XT_STR];   // [dh][x][ic(32)]

    const int tid  = threadIdx.x;
    const int lane = tid & 63;
    const int wid  = tid >> 6;
    const int l16  = lane & 15;
    const int quad = lane >> 4;

    const int h    = blockIdx.x;          // image row 0..63
    const int coff = blockIdx.y * 64;     // 0 or 64
    const int b    = blockIdx.z;

    const int cot = (wid >> 1) * 2;       // co tile base (2 tiles)
    const int pxt = (wid & 1) * 2;        // px tile base (2 tiles)

    f32x4 acc[2][2];
    #pragma unroll
    for (int i = 0; i < 2; ++i)
        #pragma unroll
        for (int j = 0; j < 2; ++j) acc[i][j] = (f32x4){0.f, 0.f, 0.f, 0.f};

    const u16* Eb = Ebf + (size_t)b * NPIX * NCH;

    for (int icc = 0; icc < 8; ++icc) {
        const int ic0 = icc * 32;
        __syncthreads();
        // stage Xt[dh][x][32ic]: 3*66*4 = 792 uint4 units (8 ch each)
        for (int u = tid; u < 792; u += 256) {
            int part = u & 3;             // 8-ch quarter
            int xe   = u >> 2;            // 0..197
            int dh   = (xe * (65536 / 66 + 1)) >> 16;  // xe/66
            dh = xe / 66;
            int x  = xe - dh * 66;
            int gr = h + dh - 1;
            int gc = x - 1;
            uint4 val = make_uint4(0u, 0u, 0u, 0u);
            if ((unsigned)gr < 64u && (unsigned)gc < 64u)
                val = *(const uint4*)&Eb[((size_t)gr * 64 + gc) * NCH + ic0 + part * 8];
            *(uint4*)&Xt[(dh * 66 + x) * XT_STR + part * 8] = val;
        }
        __syncthreads();

        #pragma unroll
        for (int tap = 0; tap < 9; ++tap) {
            const int dh = tap / 3, dw = tap % 3;
            // A-frags (weights) straight from global (L2-resident)
            short8 a[2];
            #pragma unroll
            for (int i = 0; i < 2; ++i) {
                int co = coff + (cot + i) * 16 + l16;
                a[i] = *(const short8*)&wT[((size_t)co * 9 + tap) * 256 + ic0 + quad * 8];
            }
            // B-frags (im2col) from LDS
            short8 bf[2];
            #pragma unroll
            for (int j = 0; j < 2; ++j) {
                int x = (pxt + j) * 16 + l16 + dw;
                bf[j] = *(const short8*)&Xt[(dh * 66 + x) * XT_STR + quad * 8];
            }
            #pragma unroll
            for (int i = 0; i < 2; ++i)
                #pragma unroll
                for (int j = 0; j < 2; ++j)
                    acc[i][j] = __builtin_amdgcn_mfma_f32_16x16x32_bf16(a[i], bf[j], acc[i][j], 0, 0, 0);
        }
    }

    // ---- epilogue: BN + ReLU, direct stores (C-layout) ----
    #pragma unroll
    for (int i = 0; i < 2; ++i) {
        #pragma unroll
        for (int r = 0; r < 4; ++r) {
            int co = coff + (cot + i) * 16 + quad * 4 + r;
            float inv = g_cat[co] * rsqrtf(v_cat[co] + EPS);
            float mm  = m_cat[co];
            float be  = be_cat[co];
            #pragma unroll
            for (int j = 0; j < 2; ++j) {
                int wcol = (pxt + j) * 16 + l16;
                float v = (acc[i][j][r] - mm) * inv + be;
                out[((size_t)b * CI + co) * NPIX + h * 64 + wcol] = fmaxf(v, 0.f);
            }
        }
    }
}

// =====================================================================
extern "C" void kernel_launch(void* const* d_in, const int* in_sizes, int n_in,
                              void* d_out, int out_size, void* d_ws, size_t ws_size,
                              hipStream_t stream)
{
    const float* q     = (const float*)d_in[0];
    const float* s     = (const float*)d_in[1];
    const float* scale = (const float*)d_in[2];
    const float* w_v   = (const float*)d_in[3];
    const float* b_v   = (const float*)d_in[4];
    const float* w_k1  = (const float*)d_in[5];
    const float* b_k1  = (const float*)d_in[6];
    const float* w_q1  = (const float*)d_in[7];
    const float* b_q1  = (const float*)d_in[8];
    const float* w_k2  = (const float*)d_in[9];
    const float* b_k2  = (const float*)d_in[10];
    const float* w_q2  = (const float*)d_in[11];
    const float* b_q2  = (const float*)d_in[12];
    const float* w_ts  = (const float*)d_in[13];
    const float* b_ts  = (const float*)d_in[14];
    const float* g_ts  = (const float*)d_in[15];
    const float* be_ts = (const float*)d_in[16];
    const float* m_ts  = (const float*)d_in[17];
    const float* v_ts  = (const float*)d_in[18];
    const float* w_tq  = (const float*)d_in[19];
    const float* b_tq  = (const float*)d_in[20];
    const float* g_tq  = (const float*)d_in[21];
    const float* be_tq = (const float*)d_in[22];
    const float* m_tq  = (const float*)d_in[23];
    const float* v_tq  = (const float*)d_in[24];
    const float* w_cat = (const float*)d_in[25];
    const float* g_cat = (const float*)d_in[26];
    const float* be_cat= (const float*)d_in[27];
    const float* m_cat = (const float*)d_in[28];
    const float* v_cat = (const float*)d_in[29];

    float* out = (float*)d_out;
    u16* ws = (u16*)d_ws;
    const size_t SZ = (size_t)2 * CI * NPIX;   // 1,048,576 elements per buffer
    u16* kT  = ws;             // [b][n][c]
    u16* qT  = kT + SZ;        // [b][n][c]
    u16* vq  = qT + SZ;        // [b][c][n]
    u16* vs  = vq + SZ;        // [b][c][n]
    u16* tq  = vs + SZ;        // [b][c][n]
    u16* ts  = tq + SZ;        // [b][c][n]
    u16* Ebf = ts + SZ;        // [b][pix][256], 2,097,152 u16
    u16* wTb = Ebf + (size_t)2 * NPIX * NCH;   // [co][tap][ic], 294,912 u16

    dim3 blk(256);
    hipLaunchKernelGGL(proj_kernel, dim3(16, 48, 4), blk, 0, stream,
                       q, s, w_v, b_v, w_k1, b_k1, w_q1, b_q1, w_k2, b_k2, w_q2, b_q2,
                       w_ts, b_ts, g_ts, be_ts, m_ts, v_ts,
                       w_tq, b_tq, g_tq, be_tq, m_tq, v_tq,
                       kT, qT, vq, vs, tq, ts);

    hipLaunchKernelGGL(wprep_kernel, dim3(128), blk, 0, stream, w_cat, wTb);

    hipLaunchKernelGGL(attn_kernel, dim3(64, 2, 2), blk, 0, stream,
                       kT, qT, vq, vs, tq, ts, scale, out, Ebf);

    hipLaunchKernelGGL(conv_kernel, dim3(64, 2, 2), blk, 0, stream,
                       Ebf, wTb, g_cat, be_cat, m_cat, v_cat, out);
}

// Round 5
// 325.863 us; speedup vs baseline: 4.8867x; 1.1289x over previous
//
#include <hip/hip_runtime.h>
#include <hip/hip_bf16.h>

#define NPIX 4096   // H*W
#define NCH  256    // input channels
#define CI   128    // inter channels
#define EPS  1e-5f

typedef unsigned short u16;
typedef __attribute__((ext_vector_type(8))) short short8;   // 8 bf16 (4 VGPRs)
typedef __attribute__((ext_vector_type(4))) float f32x4;    // MFMA C/D

// ---------- bf16 bit helpers ----------
__device__ __forceinline__ float bfu2f(u16 u) {
    union { unsigned int i; float f; } x; x.i = ((unsigned int)u) << 16; return x.f;
}
__device__ __forceinline__ u16 f2bfu(float f) {
    union { float ff; unsigned int i; } x; x.ff = f;
    unsigned int r = x.i + 0x7FFFu + ((x.i >> 16) & 1u);
    return (u16)(r >> 16);
}

// =====================================================================
// Kernel 0: transpose inputs to bf16 xT[b*2+src][n][c].
// Grid (64, 4): 64 n-chunks of 64, (b,src). Thread: oct=t&31, nl=t>>5.
// =====================================================================
__global__ __launch_bounds__(256) void xtrans_kernel(
    const float* __restrict__ xq, const float* __restrict__ xs,
    u16* __restrict__ xT)
{
    const int tid = threadIdx.x;
    const int oct = tid & 31;          // 8-channel octet 0..31
    const int nl  = tid >> 5;          // 0..7
    const int bz  = blockIdx.y;        // b*2+src
    const int b   = bz >> 1, src = bz & 1;
    const float* x = (src ? xs : xq) + (size_t)b * NCH * NPIX;

    #pragma unroll
    for (int k = 0; k < 8; ++k) {
        int n = blockIdx.x * 64 + k * 8 + nl;
        union { u16 u[8]; uint4 v; } pk;
        #pragma unroll
        for (int j = 0; j < 8; ++j)
            pk.u[j] = f2bfu(x[(size_t)(oct * 8 + j) * NPIX + n]);
        *(uint4*)&xT[((size_t)bz * NPIX + n) * 256 + oct * 8] = pk.v;
    }
}

// =====================================================================
// Kernel 0b: pack proj weights to bf16 Wbf[src][384][256].
// Order per src: v(0..127), k(128..191), q(192..255), t(256..383).
// src=0 uses k1/q1/tq (q-branch), src=1 uses k2/q2/ts (s-branch).
// =====================================================================
__global__ __launch_bounds__(256) void wprep2_kernel(
    const float* __restrict__ w_v,
    const float* __restrict__ w_k1, const float* __restrict__ w_q1,
    const float* __restrict__ w_k2, const float* __restrict__ w_q2,
    const float* __restrict__ w_ts, const float* __restrict__ w_tq,
    u16* __restrict__ Wbf)
{
    int idx = blockIdx.x * 256 + threadIdx.x;   // 0..196607
    int src = idx / 98304;
    int r   = idx - src * 98304;
    int o   = r >> 8, c = r & 255;
    float v;
    if (o < 128)      v = w_v[(size_t)o * 256 + c];
    else if (o < 192) v = (src ? w_k2 : w_k1)[(size_t)(o - 128) * 256 + c];
    else if (o < 256) v = (src ? w_q2 : w_q1)[(size_t)(o - 192) * 256 + c];
    else              v = (src ? w_ts : w_tq)[(size_t)(o - 256) * 256 + c];
    Wbf[idx] = f2bfu(v);
}

// =====================================================================
// Kernel 1: MFMA proj GEMM. Per block: one (b,src), 64 pixels, 384 out-ch.
// A = Wbf rows (global/L2), B = xT tile staged to LDS [px][c].
// Wave w: o-range w*96..+95 (6 ot x 16), all 64 px (4 pt x 16), K=256.
// Outputs: v->vq/vs [c][n]; k,q->kT/qT [n][c] via LDS transpose;
// t->tq/ts [c][n] with BN. Bias folded into acc init.
// =====================================================================
__global__ __launch_bounds__(256) void proj2_kernel(
    const u16* __restrict__ xT,   // [b*2+src][n][256]
    const u16* __restrict__ Wbf,  // [src][384][256]
    const float* __restrict__ b_v,
    const float* __restrict__ b_k1, const float* __restrict__ b_q1,
    const float* __restrict__ b_k2, const float* __restrict__ b_q2,
    const float* __restrict__ b_ts, const float* __restrict__ g_ts,
    const float* __restrict__ be_ts, const float* __restrict__ m_ts,
    const float* __restrict__ v_ts,
    const float* __restrict__ b_tq, const float* __restrict__ g_tq,
    const float* __restrict__ be_tq, const float* __restrict__ m_tq,
    const float* __restrict__ v_tq,
    u16* __restrict__ kT, u16* __restrict__ qT,
    u16* __restrict__ vq, u16* __restrict__ vs,
    u16* __restrict__ tq, u16* __restrict__ ts)
{
    __shared__ u16 Xs[64 * 264];   // [px][c], pad 8
    __shared__ u16 KQ[64 * 136];   // [px][k0..63 | q0..63]

    const int tid  = threadIdx.x;
    const int lane = tid & 63;
    const int wid  = tid >> 6;
    const int l16  = lane & 15;
    const int quad = lane >> 4;

    const int n0  = blockIdx.x * 64;
    const int bz  = blockIdx.z;
    const int b   = bz >> 1, src = bz & 1;

    // ---- stage x tile ----
    const u16* xb = xT + ((size_t)bz * NPIX + n0) * 256;
    #pragma unroll
    for (int k = 0; k < 8; ++k) {
        int idx = tid + k * 256;
        int row = idx >> 5, seg = idx & 31;
        *(uint4*)&Xs[row * 264 + seg * 8] = *(const uint4*)&xb[(size_t)row * 256 + seg * 8];
    }
    __syncthreads();

    const u16* W = Wbf + (size_t)src * 384 * 256;
    const int o0w = wid * 96;
    const float* bk = src ? b_k2 : b_k1;
    const float* bq = src ? b_q2 : b_q1;
    const float* bt = src ? b_ts : b_tq;

    // ---- acc init = bias ----
    f32x4 acc[24];
    #pragma unroll
    for (int ot = 0; ot < 6; ++ot) {
        int ob = o0w + ot * 16 + quad * 4;
        const float* bp;
        if (ob < 128)      bp = b_v + ob;
        else if (ob < 192) bp = bk + (ob - 128);
        else if (ob < 256) bp = bq + (ob - 192);
        else               bp = bt + (ob - 256);
        float4 b4 = *(const float4*)bp;
        f32x4 iv = (f32x4){b4.x, b4.y, b4.z, b4.w};
        #pragma unroll
        for (int pt = 0; pt < 4; ++pt) acc[ot * 4 + pt] = iv;
    }

    // ---- GEMM main loop ----
    #pragma unroll
    for (int kc = 0; kc < 8; ++kc) {
        short8 bfr[4];
        #pragma unroll
        for (int pt = 0; pt < 4; ++pt)
            bfr[pt] = *(const short8*)&Xs[(pt * 16 + l16) * 264 + kc * 32 + quad * 8];
        #pragma unroll
        for (int ot = 0; ot < 6; ++ot) {
            short8 a = *(const short8*)&W[(size_t)(o0w + ot * 16 + l16) * 256 + kc * 32 + quad * 8];
            #pragma unroll
            for (int pt = 0; pt < 4; ++pt)
                acc[ot * 4 + pt] = __builtin_amdgcn_mfma_f32_16x16x32_bf16(a, bfr[pt], acc[ot * 4 + pt], 0, 0, 0);
        }
    }

    // ---- epilogue ----
    #pragma unroll
    for (int ot = 0; ot < 6; ++ot) {
        int ob = o0w + ot * 16;
        #pragma unroll
        for (int pt = 0; pt < 4; ++pt) {
            int px = pt * 16 + l16;
            f32x4 v4 = acc[ot * 4 + pt];
            if (ob < 128) {
                u16* dst = src ? vs : vq;
                #pragma unroll
                for (int r = 0; r < 4; ++r)
                    dst[((size_t)b * CI + ob + quad * 4 + r) * NPIX + n0 + px] = f2bfu(v4[r]);
            } else if (ob < 256) {
                int colb = (ob < 192) ? (ob - 128) : (64 + ob - 192);
                #pragma unroll
                for (int r = 0; r < 4; ++r)
                    KQ[px * 136 + colb + quad * 4 + r] = f2bfu(v4[r]);
            } else {
                const float* g  = src ? g_ts  : g_tq;
                const float* be = src ? be_ts : be_tq;
                const float* mm = src ? m_ts  : m_tq;
                const float* vv = src ? v_ts  : v_tq;
                u16* dst = src ? ts : tq;
                #pragma unroll
                for (int r = 0; r < 4; ++r) {
                    int oc = ob - 256 + quad * 4 + r;
                    float inv = g[oc] * rsqrtf(vv[oc] + EPS);
                    dst[((size_t)b * CI + oc) * NPIX + n0 + px] =
                        f2bfu((v4[r] - mm[oc]) * inv + be[oc]);
                }
            }
        }
    }
    __syncthreads();

    // ---- cooperative kT/qT store ([n][c] packed) ----
    const int chb = src ? 64 : 0;
    #pragma unroll
    for (int u = 0; u < 4; ++u) {
        int idx = tid + u * 256;           // 0..1023
        int px = idx >> 4, oct = idx & 15;
        uint4 val = *(const uint4*)&KQ[px * 136 + oct * 8];
        if (oct < 8)
            *(uint4*)&kT[((size_t)b * NPIX + n0 + px) * CI + chb + oct * 8] = val;
        else
            *(uint4*)&qT[((size_t)b * NPIX + n0 + px) * CI + chb + (oct - 8) * 8] = val;
    }
}

// =====================================================================
// Kernel 1b: transpose conv weights to bf16 wT[co][tap][ic].
// =====================================================================
__global__ __launch_bounds__(256) void wprep_kernel(
    const float* __restrict__ w_cat, u16* __restrict__ wT)
{
    const int co = blockIdx.x;
    const float* srcb = w_cat + (size_t)co * 2304;
    u16* dstb = wT + (size_t)co * 2304;
    for (int t = threadIdx.x; t < 2304; t += 256) {
        int ic = t / 9, tap = t - ic * 9;
        dstb[tap * 256 + ic] = f2bfu(srcb[t]);
    }
}

// =====================================================================
// Kernel 2: dual flash attention with MFMA (bf16 16x16x32). Unchanged.
// =====================================================================
#define QS_OFF 0
#define KS_OFF 8704
#define VT_OFF 17408
#define PS_OFF 26624
#define SMEM_U16 31232

__global__ __launch_bounds__(256) void attn_kernel(
    const u16* __restrict__ kT, const u16* __restrict__ qT,
    const u16* __restrict__ vq, const u16* __restrict__ vs,
    const u16* __restrict__ tq, const u16* __restrict__ ts,
    const float* __restrict__ scale_p,
    float* __restrict__ out, u16* __restrict__ Ebf)
{
    __shared__ u16 smem[SMEM_U16];
    u16* Qs = smem + QS_OFF;
    u16* Ks = smem + KS_OFF;
    u16* Vt = smem + VT_OFF;
    u16* Ps = smem + PS_OFF;

    const int tid  = threadIdx.x;
    const int lane = tid & 63;
    const int wid  = tid >> 6;
    const int l16  = lane & 15;
    const int quad = lane >> 4;
    const int strip = wid * 16;

    const int n0 = blockIdx.x * 64;
    const int at = blockIdx.y;
    const int b  = blockIdx.z;

    const u16* Qg = at ? qT : kT;
    const u16* Kg = at ? kT : qT;
    const u16* Vg = at ? vq : vs;
    const u16* Tg = at ? tq : ts;
    float* outE   = out + (size_t)(at ? 1 : 2) * 1048576;
    const int ch0 = at ? 0 : 128;

    {
        const u16* Qb = Qg + ((size_t)b * NPIX + n0) * CI;
        #pragma unroll
        for (int k = 0; k < 4; ++k) {
            int idx = tid + k * 256;
            int row = idx >> 4, seg = idx & 15;
            *(uint4*)&Qs[row * 136 + seg * 8] =
                *(const uint4*)&Qb[(size_t)row * CI + seg * 8];
        }
    }
    __syncthreads();

    short8 af[4];
    #pragma unroll
    for (int kc = 0; kc < 4; ++kc)
        af[kc] = *(const short8*)&Qs[(strip + l16) * 136 + kc * 32 + quad * 8];

    f32x4 o[8];
    #pragma unroll
    for (int ct = 0; ct < 8; ++ct) o[ct] = (f32x4){0.f, 0.f, 0.f, 0.f};
    float M[4], L[4];
    #pragma unroll
    for (int r = 0; r < 4; ++r) { M[r] = -INFINITY; L[r] = 0.f; }

    const u16* KgB = Kg + (size_t)b * NPIX * CI;
    const u16* VgB = Vg + (size_t)b * CI * NPIX;

    for (int mt = 0; mt < 64; ++mt) {
        const int m0 = mt * 64;
        __syncthreads();
        {
            const u16* Kb = KgB + (size_t)m0 * CI;
            const u16* Vb = VgB + m0;
            #pragma unroll
            for (int k = 0; k < 4; ++k) {
                int idx = tid + k * 256;
                int row = idx >> 4, seg = idx & 15;
                *(uint4*)&Ks[row * 136 + seg * 8] =
                    *(const uint4*)&Kb[(size_t)row * CI + seg * 8];
            }
            #pragma unroll
            for (int k = 0; k < 4; ++k) {
                int idx = tid + k * 256;
                int c = idx >> 3, seg = idx & 7;
                *(uint4*)&Vt[c * 72 + seg * 8] =
                    *(const uint4*)&Vb[(size_t)c * NPIX + seg * 8];
            }
        }
        __syncthreads();

        f32x4 sv[4];
        #pragma unroll
        for (int ct = 0; ct < 4; ++ct) {
            f32x4 c = (f32x4){0.f, 0.f, 0.f, 0.f};
            #pragma unroll
            for (int kc = 0; kc < 4; ++kc) {
                short8 bf = *(const short8*)&Ks[(ct * 16 + l16) * 136 + kc * 32 + quad * 8];
                c = __builtin_amdgcn_mfma_f32_16x16x32_bf16(af[kc], bf, c, 0, 0, 0);
            }
            sv[ct] = c;
        }

        #pragma unroll
        for (int r = 0; r < 4; ++r) {
            float tm = fmaxf(fmaxf(sv[0][r], sv[1][r]), fmaxf(sv[2][r], sv[3][r]));
            tm = fmaxf(tm, __shfl_xor(tm, 1));
            tm = fmaxf(tm, __shfl_xor(tm, 2));
            tm = fmaxf(tm, __shfl_xor(tm, 4));
            tm = fmaxf(tm, __shfl_xor(tm, 8));
            float nm = fmaxf(M[r], tm);
            float al = __expf(M[r] - nm);
            M[r] = nm;
            float p0 = __expf(sv[0][r] - nm);
            float p1 = __expf(sv[1][r] - nm);
            float p2 = __expf(sv[2][r] - nm);
            float p3 = __expf(sv[3][r] - nm);
            float tsum = p0 + p1 + p2 + p3;
            tsum += __shfl_xor(tsum, 1);
            tsum += __shfl_xor(tsum, 2);
            tsum += __shfl_xor(tsum, 4);
            tsum += __shfl_xor(tsum, 8);
            L[r] = L[r] * al + tsum;
            #pragma unroll
            for (int ct = 0; ct < 8; ++ct) o[ct][r] *= al;
            int prow = strip + quad * 4 + r;
            Ps[prow * 72 + 0 * 16 + l16] = f2bfu(p0);
            Ps[prow * 72 + 1 * 16 + l16] = f2bfu(p1);
            Ps[prow * 72 + 2 * 16 + l16] = f2bfu(p2);
            Ps[prow * 72 + 3 * 16 + l16] = f2bfu(p3);
        }
        __syncthreads();

        short8 ap[2];
        #pragma unroll
        for (int kc = 0; kc < 2; ++kc)
            ap[kc] = *(const short8*)&Ps[(strip + l16) * 72 + kc * 32 + quad * 8];
        #pragma unroll
        for (int ct = 0; ct < 8; ++ct) {
            #pragma unroll
            for (int kc = 0; kc < 2; ++kc) {
                short8 bv = *(const short8*)&Vt[(ct * 16 + l16) * 72 + kc * 32 + quad * 8];
                o[ct] = __builtin_amdgcn_mfma_f32_16x16x32_bf16(ap[kc], bv, o[ct], 0, 0, 0);
            }
        }
    }

    __syncthreads();
    float* Of = (float*)smem;
    #pragma unroll
    for (int r = 0; r < 4; ++r) {
        float inv = 1.f / L[r];
        int row = strip + quad * 4 + r;
        #pragma unroll
        for (int ct = 0; ct < 8; ++ct)
            Of[(ct * 16 + l16) * 68 + row] = o[ct][r] * inv;
    }
    __syncthreads();
    float scale = *scale_p;
    const u16* Tb = Tg + (size_t)b * CI * NPIX + n0;
    float* Ob = outE + (size_t)b * CI * NPIX + n0;
    for (int idx = tid; idx < 128 * 64; idx += 256) {
        int c = idx >> 6, r = idx & 63;
        float v = scale * Of[c * 68 + r] + bfu2f(Tb[(size_t)c * NPIX + r]);
        Ob[(size_t)c * NPIX + r] = v;
        Ebf[((size_t)b * NPIX + n0 + r) * NCH + ch0 + c] = f2bfu(v);
    }
}

// =====================================================================
// Kernel 3: 3x3 conv as MFMA implicit GEMM + BN + ReLU. Unchanged.
// =====================================================================
#define XT_STR 40

__global__ __launch_bounds__(256) void conv_kernel(
    const u16* __restrict__ Ebf,
    const u16* __restrict__ wT,
    const float* __restrict__ g_cat, const float* __restrict__ be_cat,
    const float* __restrict__ m_cat, const float* __restrict__ v_cat,
    float* __restrict__ out)
{
    __shared__ u16 Xt[3 * 66 * XT_STR];

    const int tid  = threadIdx.x;
    const int lane = tid & 63;
    const int wid  = tid >> 6;
    const int l16  = lane & 15;
    const int quad = lane >> 4;

    const int h    = blockIdx.x;
    const int coff = blockIdx.y * 64;
    const int b    = blockIdx.z;

    const int cot = (wid >> 1) * 2;
    const int pxt = (wid & 1) * 2;

    f32x4 acc[2][2];
    #pragma unroll
    for (int i = 0; i < 2; ++i)
        #pragma unroll
        for (int j = 0; j < 2; ++j) acc[i][j] = (f32x4){0.f, 0.f, 0.f, 0.f};

    const u16* Eb = Ebf + (size_t)b * NPIX * NCH;

    for (int icc = 0; icc < 8; ++icc) {
        const int ic0 = icc * 32;
        __syncthreads();
        for (int u = tid; u < 792; u += 256) {
            int part = u & 3;
            int xe   = u >> 2;
            int dh   = xe / 66;
            int x  = xe - dh * 66;
            int gr = h + dh - 1;
            int gc = x - 1;
            uint4 val = make_uint4(0u, 0u, 0u, 0u);
            if ((unsigned)gr < 64u && (unsigned)gc < 64u)
                val = *(const uint4*)&Eb[((size_t)gr * 64 + gc) * NCH + ic0 + part * 8];
            *(uint4*)&Xt[(dh * 66 + x) * XT_STR + part * 8] = val;
        }
        __syncthreads();

        #pragma unroll
        for (int tap = 0; tap < 9; ++tap) {
            const int dh = tap / 3, dw = tap % 3;
            short8 a[2];
            #pragma unroll
            for (int i = 0; i < 2; ++i) {
                int co = coff + (cot + i) * 16 + l16;
                a[i] = *(const short8*)&wT[((size_t)co * 9 + tap) * 256 + ic0 + quad * 8];
            }
            short8 bf[2];
            #pragma unroll
            for (int j = 0; j < 2; ++j) {
                int x = (pxt + j) * 16 + l16 + dw;
                bf[j] = *(const short8*)&Xt[(dh * 66 + x) * XT_STR + quad * 8];
            }
            #pragma unroll
            for (int i = 0; i < 2; ++i)
                #pragma unroll
                for (int j = 0; j < 2; ++j)
                    acc[i][j] = __builtin_amdgcn_mfma_f32_16x16x32_bf16(a[i], bf[j], acc[i][j], 0, 0, 0);
        }
    }

    #pragma unroll
    for (int i = 0; i < 2; ++i) {
        #pragma unroll
        for (int r = 0; r < 4; ++r) {
            int co = coff + (cot + i) * 16 + quad * 4 + r;
            float inv = g_cat[co] * rsqrtf(v_cat[co] + EPS);
            float mm  = m_cat[co];
            float be  = be_cat[co];
            #pragma unroll
            for (int j = 0; j < 2; ++j) {
                int wcol = (pxt + j) * 16 + l16;
                float v = (acc[i][j][r] - mm) * inv + be;
                out[((size_t)b * CI + co) * NPIX + h * 64 + wcol] = fmaxf(v, 0.f);
            }
        }
    }
}

// =====================================================================
extern "C" void kernel_launch(void* const* d_in, const int* in_sizes, int n_in,
                              void* d_out, int out_size, void* d_ws, size_t ws_size,
                              hipStream_t stream)
{
    const float* q     = (const float*)d_in[0];
    const float* s     = (const float*)d_in[1];
    const float* scale = (const float*)d_in[2];
    const float* w_v   = (const float*)d_in[3];
    const float* b_v   = (const float*)d_in[4];
    const float* w_k1  = (const float*)d_in[5];
    const float* b_k1  = (const float*)d_in[6];
    const float* w_q1  = (const float*)d_in[7];
    const float* b_q1  = (const float*)d_in[8];
    const float* w_k2  = (const float*)d_in[9];
    const float* b_k2  = (const float*)d_in[10];
    const float* w_q2  = (const float*)d_in[11];
    const float* b_q2  = (const float*)d_in[12];
    const float* w_ts  = (const float*)d_in[13];
    const float* b_ts  = (const float*)d_in[14];
    const float* g_ts  = (const float*)d_in[15];
    const float* be_ts = (const float*)d_in[16];
    const float* m_ts  = (const float*)d_in[17];
    const float* v_ts  = (const float*)d_in[18];
    const float* w_tq  = (const float*)d_in[19];
    const float* b_tq  = (const float*)d_in[20];
    const float* g_tq  = (const float*)d_in[21];
    const float* be_tq = (const float*)d_in[22];
    const float* m_tq  = (const float*)d_in[23];
    const float* v_tq  = (const float*)d_in[24];
    const float* w_cat = (const float*)d_in[25];
    const float* g_cat = (const float*)d_in[26];
    const float* be_cat= (const float*)d_in[27];
    const float* m_cat = (const float*)d_in[28];
    const float* v_cat = (const float*)d_in[29];

    float* out = (float*)d_out;
    u16* ws = (u16*)d_ws;
    const size_t SZ = (size_t)2 * CI * NPIX;        // 1,048,576 u16 per buffer
    u16* kT  = ws;                                   // [b][n][c]
    u16* qT  = kT + SZ;                              // [b][n][c]
    u16* vq  = qT + SZ;                              // [b][c][n]
    u16* vs  = vq + SZ;                              // [b][c][n]
    u16* tq  = vs + SZ;                              // [b][c][n]
    u16* ts  = tq + SZ;                              // [b][c][n]
    u16* Wbf = ts + SZ;                              // [src][384][256] = 196,608
    u16* B   = Wbf + 196608;
    u16* Ebf = B;                                    // [b][pix][256] = 2,097,152
    u16* wTc = B + 2097152;                          // conv wT = 294,912
    u16* xT  = B;                                    // [bz][n][256] = 4,194,304
    // lifetimes: xT (xtrans..proj2) aliases Ebf+wTc (written after proj2).

    dim3 blk(256);
    hipLaunchKernelGGL(xtrans_kernel, dim3(64, 4), blk, 0, stream, q, s, xT);
    hipLaunchKernelGGL(wprep2_kernel, dim3(768), blk, 0, stream,
                       w_v, w_k1, w_q1, w_k2, w_q2, w_ts, w_tq, Wbf);
    hipLaunchKernelGGL(proj2_kernel, dim3(64, 1, 4), blk, 0, stream,
                       xT, Wbf, b_v, b_k1, b_q1, b_k2, b_q2,
                       b_ts, g_ts, be_ts, m_ts, v_ts,
                       b_tq, g_tq, be_tq, m_tq, v_tq,
                       kT, qT, vq, vs, tq, ts);
    hipLaunchKernelGGL(wprep_kernel, dim3(128), blk, 0, stream, w_cat, wTc);
    hipLaunchKernelGGL(attn_kernel, dim3(64, 2, 2), blk, 0, stream,
                       kT, qT, vq, vs, tq, ts, scale, out, Ebf);
    hipLaunchKernelGGL(conv_kernel, dim3(64, 2, 2), blk, 0, stream,
                       Ebf, wTc, g_cat, be_cat, m_cat, v_cat, out);
}

// Round 6
// 297.550 us; speedup vs baseline: 5.3516x; 1.0952x over previous
//
#include <hip/hip_runtime.h>
#include <hip/hip_bf16.h>

#define NPIX 4096   // H*W
#define NCH  256    // input channels
#define CI   128    // inter channels
#define EPS  1e-5f

typedef unsigned short u16;
typedef __attribute__((ext_vector_type(8))) short short8;   // 8 bf16 (4 VGPRs)
typedef __attribute__((ext_vector_type(4))) float f32x4;    // MFMA C/D

// ---------- bf16 bit helpers ----------
__device__ __forceinline__ float bfu2f(u16 u) {
    union { unsigned int i; float f; } x; x.i = ((unsigned int)u) << 16; return x.f;
}
__device__ __forceinline__ u16 f2bfu(float f) {
    union { float ff; unsigned int i; } x; x.ff = f;
    unsigned int r = x.i + 0x7FFFu + ((x.i >> 16) & 1u);
    return (u16)(r >> 16);
}

// =====================================================================
// Kernel 0: transpose inputs to bf16 xT[b*2+src][n][c].
// =====================================================================
__global__ __launch_bounds__(256) void xtrans_kernel(
    const float* __restrict__ xq, const float* __restrict__ xs,
    u16* __restrict__ xT)
{
    const int tid = threadIdx.x;
    const int oct = tid & 31;
    const int nl  = tid >> 5;
    const int bz  = blockIdx.y;
    const int b   = bz >> 1, src = bz & 1;
    const float* x = (src ? xs : xq) + (size_t)b * NCH * NPIX;

    #pragma unroll
    for (int k = 0; k < 8; ++k) {
        int n = blockIdx.x * 64 + k * 8 + nl;
        union { u16 u[8]; uint4 v; } pk;
        #pragma unroll
        for (int j = 0; j < 8; ++j)
            pk.u[j] = f2bfu(x[(size_t)(oct * 8 + j) * NPIX + n]);
        *(uint4*)&xT[((size_t)bz * NPIX + n) * 256 + oct * 8] = pk.v;
    }
}

// =====================================================================
// Kernel 0b: pack proj weights to bf16 Wbf[src][384][256].
// =====================================================================
__global__ __launch_bounds__(256) void wprep2_kernel(
    const float* __restrict__ w_v,
    const float* __restrict__ w_k1, const float* __restrict__ w_q1,
    const float* __restrict__ w_k2, const float* __restrict__ w_q2,
    const float* __restrict__ w_ts, const float* __restrict__ w_tq,
    u16* __restrict__ Wbf)
{
    int idx = blockIdx.x * 256 + threadIdx.x;
    int src = idx / 98304;
    int r   = idx - src * 98304;
    int o   = r >> 8, c = r & 255;
    float v;
    if (o < 128)      v = w_v[(size_t)o * 256 + c];
    else if (o < 192) v = (src ? w_k2 : w_k1)[(size_t)(o - 128) * 256 + c];
    else if (o < 256) v = (src ? w_q2 : w_q1)[(size_t)(o - 192) * 256 + c];
    else              v = (src ? w_ts : w_tq)[(size_t)(o - 256) * 256 + c];
    Wbf[idx] = f2bfu(v);
}

// =====================================================================
// Kernel 1: MFMA proj GEMM (unchanged from round 5).
// =====================================================================
__global__ __launch_bounds__(256) void proj2_kernel(
    const u16* __restrict__ xT, const u16* __restrict__ Wbf,
    const float* __restrict__ b_v,
    const float* __restrict__ b_k1, const float* __restrict__ b_q1,
    const float* __restrict__ b_k2, const float* __restrict__ b_q2,
    const float* __restrict__ b_ts, const float* __restrict__ g_ts,
    const float* __restrict__ be_ts, const float* __restrict__ m_ts,
    const float* __restrict__ v_ts,
    const float* __restrict__ b_tq, const float* __restrict__ g_tq,
    const float* __restrict__ be_tq, const float* __restrict__ m_tq,
    const float* __restrict__ v_tq,
    u16* __restrict__ kT, u16* __restrict__ qT,
    u16* __restrict__ vq, u16* __restrict__ vs,
    u16* __restrict__ tq, u16* __restrict__ ts)
{
    __shared__ u16 Xs[64 * 264];
    __shared__ u16 KQ[64 * 136];

    const int tid  = threadIdx.x;
    const int lane = tid & 63;
    const int wid  = tid >> 6;
    const int l16  = lane & 15;
    const int quad = lane >> 4;

    const int n0  = blockIdx.x * 64;
    const int bz  = blockIdx.z;
    const int b   = bz >> 1, src = bz & 1;

    const u16* xb = xT + ((size_t)bz * NPIX + n0) * 256;
    #pragma unroll
    for (int k = 0; k < 8; ++k) {
        int idx = tid + k * 256;
        int row = idx >> 5, seg = idx & 31;
        *(uint4*)&Xs[row * 264 + seg * 8] = *(const uint4*)&xb[(size_t)row * 256 + seg * 8];
    }
    __syncthreads();

    const u16* W = Wbf + (size_t)src * 384 * 256;
    const int o0w = wid * 96;
    const float* bk = src ? b_k2 : b_k1;
    const float* bq = src ? b_q2 : b_q1;
    const float* bt = src ? b_ts : b_tq;

    f32x4 acc[24];
    #pragma unroll
    for (int ot = 0; ot < 6; ++ot) {
        int ob = o0w + ot * 16 + quad * 4;
        const float* bp;
        if (ob < 128)      bp = b_v + ob;
        else if (ob < 192) bp = bk + (ob - 128);
        else if (ob < 256) bp = bq + (ob - 192);
        else               bp = bt + (ob - 256);
        float4 b4 = *(const float4*)bp;
        f32x4 iv = (f32x4){b4.x, b4.y, b4.z, b4.w};
        #pragma unroll
        for (int pt = 0; pt < 4; ++pt) acc[ot * 4 + pt] = iv;
    }

    #pragma unroll
    for (int kc = 0; kc < 8; ++kc) {
        short8 bfr[4];
        #pragma unroll
        for (int pt = 0; pt < 4; ++pt)
            bfr[pt] = *(const short8*)&Xs[(pt * 16 + l16) * 264 + kc * 32 + quad * 8];
        #pragma unroll
        for (int ot = 0; ot < 6; ++ot) {
            short8 a = *(const short8*)&W[(size_t)(o0w + ot * 16 + l16) * 256 + kc * 32 + quad * 8];
            #pragma unroll
            for (int pt = 0; pt < 4; ++pt)
                acc[ot * 4 + pt] = __builtin_amdgcn_mfma_f32_16x16x32_bf16(a, bfr[pt], acc[ot * 4 + pt], 0, 0, 0);
        }
    }

    #pragma unroll
    for (int ot = 0; ot < 6; ++ot) {
        int ob = o0w + ot * 16;
        #pragma unroll
        for (int pt = 0; pt < 4; ++pt) {
            int px = pt * 16 + l16;
            f32x4 v4 = acc[ot * 4 + pt];
            if (ob < 128) {
                u16* dst = src ? vs : vq;
                #pragma unroll
                for (int r = 0; r < 4; ++r)
                    dst[((size_t)b * CI + ob + quad * 4 + r) * NPIX + n0 + px] = f2bfu(v4[r]);
            } else if (ob < 256) {
                int colb = (ob < 192) ? (ob - 128) : (64 + ob - 192);
                #pragma unroll
                for (int r = 0; r < 4; ++r)
                    KQ[px * 136 + colb + quad * 4 + r] = f2bfu(v4[r]);
            } else {
                const float* g  = src ? g_ts  : g_tq;
                const float* be = src ? be_ts : be_tq;
                const float* mm = src ? m_ts  : m_tq;
                const float* vv = src ? v_ts  : v_tq;
                u16* dst = src ? ts : tq;
                #pragma unroll
                for (int r = 0; r < 4; ++r) {
                    int oc = ob - 256 + quad * 4 + r;
                    float inv = g[oc] * rsqrtf(vv[oc] + EPS);
                    dst[((size_t)b * CI + oc) * NPIX + n0 + px] =
                        f2bfu((v4[r] - mm[oc]) * inv + be[oc]);
                }
            }
        }
    }
    __syncthreads();

    const int chb = src ? 64 : 0;
    #pragma unroll
    for (int u = 0; u < 4; ++u) {
        int idx = tid + u * 256;
        int px = idx >> 4, oct = idx & 15;
        uint4 val = *(const uint4*)&KQ[px * 136 + oct * 8];
        if (oct < 8)
            *(uint4*)&kT[((size_t)b * NPIX + n0 + px) * CI + chb + oct * 8] = val;
        else
            *(uint4*)&qT[((size_t)b * NPIX + n0 + px) * CI + chb + (oct - 8) * 8] = val;
    }
}

// =====================================================================
// Kernel 1b: transpose conv weights to bf16 wT[co][tap][ic].
// =====================================================================
__global__ __launch_bounds__(256) void wprep_kernel(
    const float* __restrict__ w_cat, u16* __restrict__ wT)
{
    const int co = blockIdx.x;
    const float* srcb = w_cat + (size_t)co * 2304;
    u16* dstb = wT + (size_t)co * 2304;
    for (int t = threadIdx.x; t < 2304; t += 256) {
        int ic = t / 9, tap = t - ic * 9;
        dstb[tap * 256 + ic] = f2bfu(srcb[t]);
    }
}

// =====================================================================
// Kernel 2: dual flash attention, split-m (flash split-K).
// Each block handles 64/nseg m-tiles, writes unnormalized partial
// O (bf16 [64][128]) + per-row (M,L) f32 to ws. No Q LDS stage
// (A-fragments direct from global) -> LDS 45 KB -> 3 blocks/CU.
// Grid (64, 2, 2*nseg): z = b*nseg + seg.
// =====================================================================
#define AKS_OFF 0
#define AVT_OFF 8704
#define APS_OFF 17920
#define ASMEM_U16 22528

__global__ __launch_bounds__(256) void attn_kernel(
    const u16* __restrict__ kT, const u16* __restrict__ qT,
    const u16* __restrict__ vq, const u16* __restrict__ vs,
    u16* __restrict__ Opart, float* __restrict__ MLpart, int nseg)
{
    __shared__ u16 smem[ASMEM_U16];
    u16* Ks = smem + AKS_OFF;   // [m64][c128+pad8] stride 136
    u16* Vt = smem + AVT_OFF;   // [c128][m64+pad8] stride 72
    u16* Ps = smem + APS_OFF;   // [m64][r64+pad8]  stride 72

    const int tid  = threadIdx.x;
    const int lane = tid & 63;
    const int wid  = tid >> 6;
    const int l16  = lane & 15;
    const int quad = lane >> 4;
    const int strip = wid * 16;

    const int nt = blockIdx.x;
    const int n0 = nt * 64;
    const int at = blockIdx.y;
    const int z  = blockIdx.z;
    const int b  = z / nseg;
    const int seg = z - b * nseg;

    const u16* Qg = at ? qT : kT;
    const u16* Kg = at ? kT : qT;
    const u16* Vg = at ? vq : vs;

    // A-fragments of Q direct from global ([n][c] layout, 16B aligned)
    short8 af[4];
    {
        const u16* Qb = Qg + ((size_t)b * NPIX + n0 + strip + l16) * CI;
        #pragma unroll
        for (int kc = 0; kc < 4; ++kc)
            af[kc] = *(const short8*)&Qb[kc * 32 + quad * 8];
    }

    f32x4 o[8];
    #pragma unroll
    for (int ct = 0; ct < 8; ++ct) o[ct] = (f32x4){0.f, 0.f, 0.f, 0.f};
    float M[4], L[4];
    #pragma unroll
    for (int r = 0; r < 4; ++r) { M[r] = -INFINITY; L[r] = 0.f; }

    const u16* KgB = Kg + (size_t)b * NPIX * CI;
    const u16* VgB = Vg + (size_t)b * CI * NPIX;

    const int mt0 = seg * (64 / nseg);
    const int mt1 = mt0 + (64 / nseg);

    for (int mt = mt0; mt < mt1; ++mt) {
        const int m0 = mt * 64;
        __syncthreads();   // Ks/Vt/Ps from prev iter fully consumed
        {
            const u16* Kb = KgB + (size_t)m0 * CI;
            const u16* Vb = VgB + m0;
            #pragma unroll
            for (int k = 0; k < 4; ++k) {
                int idx = tid + k * 256;
                int row = idx >> 4, sg = idx & 15;
                *(uint4*)&Ks[row * 136 + sg * 8] =
                    *(const uint4*)&Kb[(size_t)row * CI + sg * 8];
            }
            #pragma unroll
            for (int k = 0; k < 4; ++k) {
                int idx = tid + k * 256;
                int c = idx >> 3, sg = idx & 7;
                *(uint4*)&Vt[c * 72 + sg * 8] =
                    *(const uint4*)&Vb[(size_t)c * NPIX + sg * 8];
            }
        }
        __syncthreads();

        // ---- S = Q K^T ----
        f32x4 sv[4];
        #pragma unroll
        for (int ct = 0; ct < 4; ++ct) {
            f32x4 c = (f32x4){0.f, 0.f, 0.f, 0.f};
            #pragma unroll
            for (int kc = 0; kc < 4; ++kc) {
                short8 bf = *(const short8*)&Ks[(ct * 16 + l16) * 136 + kc * 32 + quad * 8];
                c = __builtin_amdgcn_mfma_f32_16x16x32_bf16(af[kc], bf, c, 0, 0, 0);
            }
            sv[ct] = c;
        }

        // ---- online softmax ----
        #pragma unroll
        for (int r = 0; r < 4; ++r) {
            float tm = fmaxf(fmaxf(sv[0][r], sv[1][r]), fmaxf(sv[2][r], sv[3][r]));
            tm = fmaxf(tm, __shfl_xor(tm, 1));
            tm = fmaxf(tm, __shfl_xor(tm, 2));
            tm = fmaxf(tm, __shfl_xor(tm, 4));
            tm = fmaxf(tm, __shfl_xor(tm, 8));
            float nm = fmaxf(M[r], tm);
            float al = __expf(M[r] - nm);
            M[r] = nm;
            float p0 = __expf(sv[0][r] - nm);
            float p1 = __expf(sv[1][r] - nm);
            float p2 = __expf(sv[2][r] - nm);
            float p3 = __expf(sv[3][r] - nm);
            float tsum = p0 + p1 + p2 + p3;
            tsum += __shfl_xor(tsum, 1);
            tsum += __shfl_xor(tsum, 2);
            tsum += __shfl_xor(tsum, 4);
            tsum += __shfl_xor(tsum, 8);
            L[r] = L[r] * al + tsum;
            #pragma unroll
            for (int ct = 0; ct < 8; ++ct) o[ct][r] *= al;
            int prow = strip + quad * 4 + r;
            Ps[prow * 72 + 0 * 16 + l16] = f2bfu(p0);
            Ps[prow * 72 + 1 * 16 + l16] = f2bfu(p1);
            Ps[prow * 72 + 2 * 16 + l16] = f2bfu(p2);
            Ps[prow * 72 + 3 * 16 + l16] = f2bfu(p3);
        }
        __syncthreads();

        // ---- PV ----
        short8 ap[2];
        #pragma unroll
        for (int kc = 0; kc < 2; ++kc)
            ap[kc] = *(const short8*)&Ps[(strip + l16) * 72 + kc * 32 + quad * 8];
        #pragma unroll
        for (int ct = 0; ct < 8; ++ct) {
            #pragma unroll
            for (int kc = 0; kc < 2; ++kc) {
                short8 bv = *(const short8*)&Vt[(ct * 16 + l16) * 72 + kc * 32 + quad * 8];
                o[ct] = __builtin_amdgcn_mfma_f32_16x16x32_bf16(ap[kc], bv, o[ct], 0, 0, 0);
            }
        }
    }

    // ---- store partials: O bf16 [row][ch], (M,L) f32 per row ----
    const size_t tile = (((size_t)(at * 2 + b) * 64 + nt) * nseg + seg);
    u16* Ob = Opart + tile * 8192;
    #pragma unroll
    for (int r = 0; r < 4; ++r) {
        int row = strip + quad * 4 + r;
        #pragma unroll
        for (int ct = 0; ct < 8; ++ct)
            Ob[row * 128 + ct * 16 + l16] = f2bfu(o[ct][r]);
        if (l16 == 0) {
            MLpart[(tile * 64 + row) * 2 + 0] = M[r];
            MLpart[(tile * 64 + row) * 2 + 1] = L[r];
        }
    }
}

// =====================================================================
// Kernel 2b: combine split-m partials + epilogue (t add, out + Ebf).
// Grid (64, 2, 2).
// =====================================================================
__global__ __launch_bounds__(256) void attn_combine_kernel(
    const u16* __restrict__ Opart, const float* __restrict__ MLpart,
    const u16* __restrict__ tq, const u16* __restrict__ ts,
    const float* __restrict__ scale_p,
    float* __restrict__ out, u16* __restrict__ Ebf, int nseg)
{
    __shared__ float Of[128 * 68];
    __shared__ float wseg[64][4];

    const int tid = threadIdx.x;
    const int nt = blockIdx.x;
    const int n0 = nt * 64;
    const int at = blockIdx.y;
    const int b  = blockIdx.z;

    const u16* Tg = at ? tq : ts;
    float* outE   = out + (size_t)(at ? 1 : 2) * 1048576;
    const int ch0 = at ? 0 : 128;
    const size_t tbase = ((size_t)(at * 2 + b) * 64 + nt) * nseg;

    // phase 0: per-row merge weights
    if (tid < 64) {
        int r = tid;
        float Mi[4], Li[4];
        float Mg = -INFINITY;
        for (int s = 0; s < nseg; ++s) {
            Mi[s] = MLpart[((tbase + s) * 64 + r) * 2 + 0];
            Li[s] = MLpart[((tbase + s) * 64 + r) * 2 + 1];
            Mg = fmaxf(Mg, Mi[s]);
        }
        float Lg = 0.f;
        for (int s = 0; s < nseg; ++s) Lg += Li[s] * __expf(Mi[s] - Mg);
        float invL = 1.f / Lg;
        for (int s = 0; s < nseg; ++s) wseg[r][s] = __expf(Mi[s] - Mg) * invL;
    }
    __syncthreads();

    // phase A: merge partial O -> Of[ch][row]
    #pragma unroll
    for (int k = 0; k < 4; ++k) {
        int idx = tid + k * 256;            // 1024 units of 8 ch
        int row = idx >> 4, oct = idx & 15;
        float m[8] = {0.f, 0.f, 0.f, 0.f, 0.f, 0.f, 0.f, 0.f};
        for (int s = 0; s < nseg; ++s) {
            union { uint4 v; u16 u[8]; } pk;
            pk.v = *(const uint4*)&Opart[(tbase + s) * 8192 + row * 128 + oct * 8];
            float w = wseg[row][s];
            #pragma unroll
            for (int j = 0; j < 8; ++j) m[j] += w * bfu2f(pk.u[j]);
        }
        #pragma unroll
        for (int j = 0; j < 8; ++j)
            Of[(oct * 8 + j) * 68 + row] = m[j];
    }
    __syncthreads();

    // phase B: scale + t add, write fp32 out ([c][n]) and bf16 Ebf ([n][c])
    float scale = *scale_p;
    const u16* Tb = Tg + (size_t)b * CI * NPIX + n0;
    float* Ob = outE + (size_t)b * CI * NPIX + n0;
    for (int idx = tid; idx < 128 * 64; idx += 256) {
        int c = idx >> 6, r = idx & 63;
        float v = scale * Of[c * 68 + r] + bfu2f(Tb[(size_t)c * NPIX + r]);
        Ob[(size_t)c * NPIX + r] = v;
        Ebf[((size_t)b * NPIX + n0 + r) * NCH + ch0 + c] = f2bfu(v);
    }
}

// =====================================================================
// Kernel 3: 3x3 conv as MFMA implicit GEMM + BN + ReLU. Unchanged.
// =====================================================================
#define XT_STR 40

__global__ __launch_bounds__(256) void conv_kernel(
    const u16* __restrict__ Ebf,
    const u16* __restrict__ wT,
    const float* __restrict__ g_cat, const float* __restrict__ be_cat,
    const float* __restrict__ m_cat, const float* __restrict__ v_cat,
    float* __restrict__ out)
{
    __shared__ u16 Xt[3 * 66 * XT_STR];

    const int tid  = threadIdx.x;
    const int lane = tid & 63;
    const int wid  = tid >> 6;
    const int l16  = lane & 15;
    const int quad = lane >> 4;

    const int h    = blockIdx.x;
    const int coff = blockIdx.y * 64;
    const int b    = blockIdx.z;

    const int cot = (wid >> 1) * 2;
    const int pxt = (wid & 1) * 2;

    f32x4 acc[2][2];
    #pragma unroll
    for (int i = 0; i < 2; ++i)
        #pragma unroll
        for (int j = 0; j < 2; ++j) acc[i][j] = (f32x4){0.f, 0.f, 0.f, 0.f};

    const u16* Eb = Ebf + (size_t)b * NPIX * NCH;

    for (int icc = 0; icc < 8; ++icc) {
        const int ic0 = icc * 32;
        __syncthreads();
        for (int u = tid; u < 792; u += 256) {
            int part = u & 3;
            int xe   = u >> 2;
            int dh   = xe / 66;
            int x  = xe - dh * 66;
            int gr = h + dh - 1;
            int gc = x - 1;
            uint4 val = make_uint4(0u, 0u, 0u, 0u);
            if ((unsigned)gr < 64u && (unsigned)gc < 64u)
                val = *(const uint4*)&Eb[((size_t)gr * 64 + gc) * NCH + ic0 + part * 8];
            *(uint4*)&Xt[(dh * 66 + x) * XT_STR + part * 8] = val;
        }
        __syncthreads();

        #pragma unroll
        for (int tap = 0; tap < 9; ++tap) {
            const int dh = tap / 3, dw = tap % 3;
            short8 a[2];
            #pragma unroll
            for (int i = 0; i < 2; ++i) {
                int co = coff + (cot + i) * 16 + l16;
                a[i] = *(const short8*)&wT[((size_t)co * 9 + tap) * 256 + ic0 + quad * 8];
            }
            short8 bf[2];
            #pragma unroll
            for (int j = 0; j < 2; ++j) {
                int x = (pxt + j) * 16 + l16 + dw;
                bf[j] = *(const short8*)&Xt[(dh * 66 + x) * XT_STR + quad * 8];
            }
            #pragma unroll
            for (int i = 0; i < 2; ++i)
                #pragma unroll
                for (int j = 0; j < 2; ++j)
                    acc[i][j] = __builtin_amdgcn_mfma_f32_16x16x32_bf16(a[i], bf[j], acc[i][j], 0, 0, 0);
        }
    }

    #pragma unroll
    for (int i = 0; i < 2; ++i) {
        #pragma unroll
        for (int r = 0; r < 4; ++r) {
            int co = coff + (cot + i) * 16 + quad * 4 + r;
            float inv = g_cat[co] * rsqrtf(v_cat[co] + EPS);
            float mm  = m_cat[co];
            float be  = be_cat[co];
            #pragma unroll
            for (int j = 0; j < 2; ++j) {
                int wcol = (pxt + j) * 16 + l16;
                float v = (acc[i][j][r] - mm) * inv + be;
                out[((size_t)b * CI + co) * NPIX + h * 64 + wcol] = fmaxf(v, 0.f);
            }
        }
    }
}

// =====================================================================
extern "C" void kernel_launch(void* const* d_in, const int* in_sizes, int n_in,
                              void* d_out, int out_size, void* d_ws, size_t ws_size,
                              hipStream_t stream)
{
    const float* q     = (const float*)d_in[0];
    const float* s     = (const float*)d_in[1];
    const float* scale = (const float*)d_in[2];
    const float* w_v   = (const float*)d_in[3];
    const float* b_v   = (const float*)d_in[4];
    const float* w_k1  = (const float*)d_in[5];
    const float* b_k1  = (const float*)d_in[6];
    const float* w_q1  = (const float*)d_in[7];
    const float* b_q1  = (const float*)d_in[8];
    const float* w_k2  = (const float*)d_in[9];
    const float* b_k2  = (const float*)d_in[10];
    const float* w_q2  = (const float*)d_in[11];
    const float* b_q2  = (const float*)d_in[12];
    const float* w_ts  = (const float*)d_in[13];
    const float* b_ts  = (const float*)d_in[14];
    const float* g_ts  = (const float*)d_in[15];
    const float* be_ts = (const float*)d_in[16];
    const float* m_ts  = (const float*)d_in[17];
    const float* v_ts  = (const float*)d_in[18];
    const float* w_tq  = (const float*)d_in[19];
    const float* b_tq  = (const float*)d_in[20];
    const float* g_tq  = (const float*)d_in[21];
    const float* be_tq = (const float*)d_in[22];
    const float* m_tq  = (const float*)d_in[23];
    const float* v_tq  = (const float*)d_in[24];
    const float* w_cat = (const float*)d_in[25];
    const float* g_cat = (const float*)d_in[26];
    const float* be_cat= (const float*)d_in[27];
    const float* m_cat = (const float*)d_in[28];
    const float* v_cat = (const float*)d_in[29];

    float* out = (float*)d_out;
    u16* ws = (u16*)d_ws;
    const size_t SZ = (size_t)2 * CI * NPIX;        // 1,048,576 u16 per buffer
    u16* kT  = ws;                                   // [b][n][c]
    u16* qT  = kT + SZ;                              // [b][n][c]
    u16* vq  = qT + SZ;                              // [b][c][n]
    u16* vs  = vq + SZ;                              // [b][c][n]
    u16* tq  = vs + SZ;                              // [b][c][n]
    u16* ts  = tq + SZ;                              // [b][c][n]
    u16* Wbf = ts + SZ;                              // 196,608 u16
    u16* B   = Wbf + 196608;
    u16* Ebf = B;                                    // [b][pix][256] = 2,097,152
    u16* wTc = B + 2097152;                          // conv wT = 294,912
    u16* xT  = B;                                    // [bz][n][256] = 4,194,304 (aliases Ebf+wTc, dead before attn)
    u16* Opart = wTc + 294912;                       // nseg * 256 tiles * 8192 u16

    // choose split factor by available workspace:
    //   bytes(S) = (fixed + S*2,097,152)*2 + S*131,072 ; fixed = 8,880,128 u16
    const size_t fixed_u16 = 6 * SZ + 196608 + 2097152 + 294912;
    int nseg = 1;
    {
        size_t need4 = (fixed_u16 + (size_t)4 * 2097152) * 2 + (size_t)4 * 131072;
        size_t need2 = (fixed_u16 + (size_t)2 * 2097152) * 2 + (size_t)2 * 131072;
        if (ws_size >= need4)      nseg = 4;
        else if (ws_size >= need2) nseg = 2;
    }
    float* MLpart = (float*)(Opart + (size_t)nseg * 256 * 8192);

    dim3 blk(256);
    hipLaunchKernelGGL(xtrans_kernel, dim3(64, 4), blk, 0, stream, q, s, xT);
    hipLaunchKernelGGL(wprep2_kernel, dim3(768), blk, 0, stream,
                       w_v, w_k1, w_q1, w_k2, w_q2, w_ts, w_tq, Wbf);
    hipLaunchKernelGGL(proj2_kernel, dim3(64, 1, 4), blk, 0, stream,
                       xT, Wbf, b_v, b_k1, b_q1, b_k2, b_q2,
                       b_ts, g_ts, be_ts, m_ts, v_ts,
                       b_tq, g_tq, be_tq, m_tq, v_tq,
                       kT, qT, vq, vs, tq, ts);
    hipLaunchKernelGGL(wprep_kernel, dim3(128), blk, 0, stream, w_cat, wTc);
    hipLaunchKernelGGL(attn_kernel, dim3(64, 2, 2 * nseg), blk, 0, stream,
                       kT, qT, vq, vs, Opart, MLpart, nseg);
    hipLaunchKernelGGL(attn_combine_kernel, dim3(64, 2, 2), blk, 0, stream,
                       Opart, MLpart, tq, ts, scale, out, Ebf, nseg);
    hipLaunchKernelGGL(conv_kernel, dim3(64, 2, 2), blk, 0, stream,
                       Ebf, wTc, g_cat, be_cat, m_cat, v_cat, out);
}